// Round 8
// baseline (371.352 us; speedup 1.0000x reference)
//
#include <hip/hip_runtime.h>
#include <hip/hip_bf16.h>

typedef float f32x4 __attribute__((ext_vector_type(4)));
typedef __bf16 v8bf __attribute__((ext_vector_type(8)));
typedef unsigned short us8v __attribute__((ext_vector_type(8)));

#define DD 128
#define EDGES 256000
#define NODES 50000
#define SCAN_BLOCKS 49   // 49*1024 >= 50000

__device__ __forceinline__ unsigned short f2bf(float f) {
    union { float f; unsigned u; } v; v.f = f;
    unsigned r = v.u + 0x7fffu + ((v.u >> 16) & 1u);
    return (unsigned short)(r >> 16);
}
__device__ __forceinline__ float bf2f(unsigned short u) {
    union { unsigned u; float f; } v; v.u = ((unsigned)u) << 16; return v.f;
}

// ---------------------------------------------------------------------------
// Weight prep. Packed B-fragment layout for a [K x C] matrix:
//   dst[((kt*(C/16)+ct)*64+l)*8+j] = bf16(W[(kt*32+(l>>4)*8+j)*C + ct*16+(l&15)])
// wp layout (ushorts):
//   eW1a: layer*16384 | eWbc: 32768+layer*32768 | eW2: 98304+layer*16384
//   nW1: 131072+layer*32768 | nW2: 196608+layer*16384
// ---------------------------------------------------------------------------
__global__ __launch_bounds__(512)
void pack_weights(const float* __restrict__ eW1, const float* __restrict__ eW2,
                  const float* __restrict__ nW1, const float* __restrict__ nW2,
                  unsigned short* __restrict__ wp)
{
    const int b = blockIdx.x;            // 0..47
    const int layer = b / 24;
    const int u = b % 24;
    const int t = threadIdx.x;
    const int ct0 = t >> 6, l = t & 63;
    const int lg = l >> 4, ll = l & 15;

    if (u < 8 && u >= 4) {
        // eWbc: [128 x 256], Wbc[k][c] = eW1[128 + k + (c>=128?128:0)][c&127]
        const int kt = u - 4;
        const float* W = eW1 + layer*49152;
        unsigned short* dst = wp + 32768 + layer*32768;
        #pragma unroll
        for (int h = 0; h < 2; ++h) {
            const int ct = ct0 + h*8;
            #pragma unroll
            for (int j = 0; j < 8; ++j) {
                const int k = kt*32 + lg*8 + j;
                const int cout = ct*16 + ll;
                const int row = 128 + k + ((cout >= 128) ? 128 : 0);
                const int col = cout & 127;
                dst[((kt*16 + ct)*64 + l)*8 + j] = f2bf(W[row*128 + col]);
            }
        }
        return;
    }
    const float* W; int kt; unsigned short* dst;
    if (u < 4)       { W = eW1 + layer*49152; kt = u;      dst = wp + layer*16384; }
    else if (u < 12) { W = eW2 + layer*16384; kt = u - 8;  dst = wp + 98304 + layer*16384; }
    else if (u < 20) { W = nW1 + layer*32768; kt = u - 12; dst = wp + 131072 + layer*32768; }
    else             { W = nW2 + layer*16384; kt = u - 20; dst = wp + 196608 + layer*16384; }
    #pragma unroll
    for (int j = 0; j < 8; ++j) {
        const int k = kt*32 + lg*8 + j;
        const int c = ct0*16 + ll;
        dst[((kt*8 + ct0)*64 + l)*8 + j] = f2bf(W[k*128 + c]);
    }
}

// ---------------------------------------------------------------------------
// CSR build: histogram -> 3-pass multi-block scan -> placement
// ---------------------------------------------------------------------------
__global__ void hist_kernel(const int* __restrict__ dst, int* __restrict__ deg)
{
    const int i = blockIdx.x * blockDim.x + threadIdx.x;
    if (i < EDGES) atomicAdd(&deg[dst[i]], 1);
}

__global__ __launch_bounds__(256)
void scan_pass1(const int* __restrict__ deg, int* __restrict__ bsum)
{
    __shared__ int ws[256];
    const int b = blockIdx.x, t = threadIdx.x;
    const int base = b*1024 + t*4;
    int s = 0;
    #pragma unroll
    for (int k = 0; k < 4; ++k) {
        const int idx = base + k;
        if (idx < NODES) s += deg[idx];
    }
    ws[t] = s;
    __syncthreads();
    for (int d = 128; d >= 1; d >>= 1) {
        if (t < d) ws[t] += ws[t + d];
        __syncthreads();
    }
    if (t == 0) bsum[b] = ws[0];
}

__global__ __launch_bounds__(64)
void scan_pass2(const int* __restrict__ bsum, int* __restrict__ bbase)
{
    const int t = threadIdx.x;
    const int mine = (t < SCAN_BLOCKS) ? bsum[t] : 0;
    int v = mine;
    #pragma unroll
    for (int d = 1; d < 64; d <<= 1) {
        const int u = __shfl_up(v, d);
        if (t >= d) v += u;
    }
    if (t < SCAN_BLOCKS) bbase[t] = v - mine;   // exclusive
}

__global__ __launch_bounds__(256)
void scan_pass3(const int* __restrict__ deg, const int* __restrict__ bbase,
                int* __restrict__ off, int* __restrict__ cursor)
{
    __shared__ int ws[256];
    const int b = blockIdx.x, t = threadIdx.x;
    const int base = b*1024 + t*4;
    int d4[4]; int s = 0;
    #pragma unroll
    for (int k = 0; k < 4; ++k) {
        const int idx = base + k;
        d4[k] = (idx < NODES) ? deg[idx] : 0;
        s += d4[k];
    }
    ws[t] = s;
    __syncthreads();
    for (int d = 1; d < 256; d <<= 1) {
        const int u = (t >= d) ? ws[t - d] : 0;
        __syncthreads();
        ws[t] += u;
        __syncthreads();
    }
    int run = bbase[b] + ws[t] - s;   // exclusive prefix for this thread's chunk
    #pragma unroll
    for (int k = 0; k < 4; ++k) {
        const int idx = base + k;
        if (idx < NODES) { off[idx] = run; cursor[idx] = run; run += d4[k]; }
    }
    if (b == 0 && t == 0) off[NODES] = EDGES;
}

__global__ void place_kernel(const int* __restrict__ dst, int* __restrict__ cursor,
                             int* __restrict__ elist)
{
    const int i = blockIdx.x * blockDim.x + threadIdx.x;
    if (i < EDGES) {
        const int p = atomicAdd(&cursor[dst[i]], 1);
        elist[p] = i;
    }
}

// ---------------------------------------------------------------------------
// Node projection: NG[v] = bf16(n[v] @ Wbc) stored in FRAGMENT order:
//   NGp[v*256 + ll*16 + cg]  where  cg = (original col)>>4, ll = col&15.
// A lane in the edge kernel then reads its 4 src values (cg = wc*4+ct) and
// 4 dst values (cg = 8+wc*4+ct) as two contiguous ushort4 loads.
// ---------------------------------------------------------------------------
__global__ __launch_bounds__(256)
void node_proj(const float* __restrict__ n,
               const unsigned short* __restrict__ Wbc,
               unsigned short* __restrict__ NG)
{
    __shared__ __align__(16) unsigned short A[64][136];
    const int tid = threadIdx.x;
    const long base = (long)blockIdx.x * 64;

    #pragma unroll
    for (int it = 0; it < 8; ++it) {
        const int i = tid + it*256;
        const int row = i >> 5;
        const int c = (i & 31) * 4;
        float4 v = {0.f, 0.f, 0.f, 0.f};
        if (base + row < NODES) v = *(const float4*)&n[(base + row)*DD + c];
        ushort4 o; o.x = f2bf(v.x); o.y = f2bf(v.y); o.z = f2bf(v.z); o.w = f2bf(v.w);
        *(ushort4*)&A[row][c] = o;
    }
    __syncthreads();

    const int lane = tid & 63, w = tid >> 6;
    const int wr = w >> 1, wc = w & 1;
    const int R0 = wr*32;
    const int lg = lane >> 4, ll = lane & 15;

    f32x4 acc[2][8] = {};
    #pragma unroll
    for (int kt = 0; kt < 4; ++kt) {
        const v8bf a0 = *(const v8bf*)&A[R0 + ll][kt*32 + lg*8];
        const v8bf a1 = *(const v8bf*)&A[R0 + 16 + ll][kt*32 + lg*8];
        #pragma unroll
        for (int ct = 0; ct < 8; ++ct) {
            const v8bf b = *(const v8bf*)&Wbc[((kt*16 + wc*8 + ct)*64 + lane)*8];
            acc[0][ct] = __builtin_amdgcn_mfma_f32_16x16x32_bf16(a0, b, acc[0][ct], 0, 0, 0);
            acc[1][ct] = __builtin_amdgcn_mfma_f32_16x16x32_bf16(a1, b, acc[1][ct], 0, 0, 0);
        }
    }

    // fragment-order packed store: ushort8 per (rt,j)
    #pragma unroll
    for (int rt = 0; rt < 2; ++rt)
        #pragma unroll
        for (int j = 0; j < 4; ++j) {
            const long grow = base + R0 + rt*16 + lg*4 + j;
            if (grow < NODES) {
                us8v o;
                #pragma unroll
                for (int ct = 0; ct < 8; ++ct) o[ct] = f2bf(acc[rt][ct][j]);
                *(us8v*)&NG[grow*256 + ll*16 + wc*8] = o;
            }
        }
}

// ---------------------------------------------------------------------------
// Edge MLP with precomputed node projections (dst-sorted edge order).
// NG reads are register-prefetched ushort4 loads in fragment order.
// ---------------------------------------------------------------------------
template <bool L0>
__global__ __launch_bounds__(256, 4)
void edge_mlp_ng(const void* __restrict__ e_in_v,
                 const unsigned short* __restrict__ NG,
                 const int* __restrict__ elist,
                 const int* __restrict__ srcA, const int* __restrict__ dstA,
                 const unsigned short* __restrict__ Wa,
                 const float* __restrict__ b1, const float* __restrict__ g1,
                 const float* __restrict__ be1,
                 const unsigned short* __restrict__ Wp2,
                 const float* __restrict__ b2,
                 unsigned short* __restrict__ ePw,
                 float* __restrict__ e_out)
{
    __shared__ __align__(16) unsigned short AeE[64][136];
    __shared__ __align__(16) unsigned short Sl[64][136];
    __shared__ float red[4][32][2];
    __shared__ int eidx[64], sidx[64], didx[64];

    const int tid = threadIdx.x;
    const long base = (long)blockIdx.x * 64;

    if (tid < 64) {
        const int i = elist[base + tid];
        eidx[tid] = i; sidx[tid] = srcA[i]; didx[tid] = dstA[i];
    }
    __syncthreads();

    const int lane = tid & 63, w = tid >> 6;
    const int wr = w >> 1, wc = w & 1;
    const int R0 = wr*32, C0 = wc*64;
    const int lg = lane >> 4, ll = lane & 15;

    // prefetch NG fragments (latency hides under staging + GEMM1a)
    ushort4 ngs[2][4], ngd[2][4];
    #pragma unroll
    for (int rt = 0; rt < 2; ++rt)
        #pragma unroll
        for (int j = 0; j < 4; ++j) {
            const int lr = rt*16 + lg*4 + j;
            const long sid = sidx[R0 + lr];
            const long did = didx[R0 + lr];
            ngs[rt][j] = *(const ushort4*)&NG[sid*256 + ll*16 + wc*4];
            ngd[rt][j] = *(const ushort4*)&NG[did*256 + ll*16 + 8 + wc*4];
        }

    // stage e tile
    if constexpr (L0) {
        const float* e_in = (const float*)e_in_v;
        #pragma unroll
        for (int it = 0; it < 8; ++it) {
            const int i = tid + it*256;
            const int row = i >> 5;
            const int c = (i & 31) * 4;
            const float4 v = *(const float4*)&e_in[(long)eidx[row]*DD + c];
            ushort4 o; o.x = f2bf(v.x); o.y = f2bf(v.y); o.z = f2bf(v.z); o.w = f2bf(v.w);
            *(ushort4*)&AeE[row][c] = o;
        }
    } else {
        const unsigned short* e_in = (const unsigned short*)e_in_v;
        #pragma unroll
        for (int it = 0; it < 4; ++it) {
            const int i = tid + it*256;
            const int row = i >> 4;
            const int c = (i & 15) * 8;
            *(uint4*)&AeE[row][c] = *(const uint4*)&e_in[(base + row)*DD + c];
        }
    }
    __syncthreads();

    float b1v[4], g1v[4], be1v[4], b2v[4];
    #pragma unroll
    for (int ct = 0; ct < 4; ++ct) {
        const int c = C0 + ct*16 + ll;
        b1v[ct] = b1[c]; g1v[ct] = g1[c]; be1v[ct] = be1[c]; b2v[ct] = b2[c];
    }

    // GEMM1a: eP @ W1a (K=128)
    f32x4 acc[2][4] = {};
    #pragma unroll
    for (int kt = 0; kt < 4; ++kt) {
        const v8bf a0 = *(const v8bf*)&AeE[R0 + ll][kt*32 + lg*8];
        const v8bf a1 = *(const v8bf*)&AeE[R0 + 16 + ll][kt*32 + lg*8];
        #pragma unroll
        for (int ct = 0; ct < 4; ++ct) {
            const v8bf b = *(const v8bf*)&Wa[((kt*8 + wc*4 + ct)*64 + lane)*8];
            acc[0][ct] = __builtin_amdgcn_mfma_f32_16x16x32_bf16(a0, b, acc[0][ct], 0, 0, 0);
            acc[1][ct] = __builtin_amdgcn_mfma_f32_16x16x32_bf16(a1, b, acc[1][ct], 0, 0, 0);
        }
    }

    // + NG[src] + NG[dst] from prefetched registers
    #pragma unroll
    for (int rt = 0; rt < 2; ++rt)
        #pragma unroll
        for (int j = 0; j < 4; ++j) {
            const unsigned short* ps = (const unsigned short*)&ngs[rt][j];
            const unsigned short* pd = (const unsigned short*)&ngd[rt][j];
            #pragma unroll
            for (int ct = 0; ct < 4; ++ct)
                acc[rt][ct][j] += bf2f(ps[ct]) + bf2f(pd[ct]);
        }

    // bias + LN stats
    f32x4 s[2], q[2];
    #pragma unroll
    for (int rt = 0; rt < 2; ++rt) {
        #pragma unroll
        for (int ct = 0; ct < 4; ++ct) acc[rt][ct] += b1v[ct];
        s[rt] = acc[rt][0] + acc[rt][1] + acc[rt][2] + acc[rt][3];
        q[rt] = acc[rt][0]*acc[rt][0] + acc[rt][1]*acc[rt][1]
              + acc[rt][2]*acc[rt][2] + acc[rt][3]*acc[rt][3];
    }
    #pragma unroll
    for (int off = 1; off <= 8; off <<= 1) {
        #pragma unroll
        for (int rt = 0; rt < 2; ++rt)
            #pragma unroll
            for (int j = 0; j < 4; ++j) {
                s[rt][j] += __shfl_xor(s[rt][j], off);
                q[rt][j] += __shfl_xor(q[rt][j], off);
            }
    }
    if (ll == 0) {
        #pragma unroll
        for (int rt = 0; rt < 2; ++rt)
            #pragma unroll
            for (int j = 0; j < 4; ++j) {
                red[w][rt*16 + lg*4 + j][0] = s[rt][j];
                red[w][rt*16 + lg*4 + j][1] = q[rt][j];
            }
    }
    __syncthreads();

    // LN + SiLU -> Sl
    #pragma unroll
    for (int rt = 0; rt < 2; ++rt) {
        #pragma unroll
        for (int j = 0; j < 4; ++j) {
            const int lr = rt*16 + lg*4 + j;
            const float S = red[2*wr][lr][0] + red[2*wr + 1][lr][0];
            const float Q = red[2*wr][lr][1] + red[2*wr + 1][lr][1];
            const float mu = S * (1.0f/DD);
            const float var = Q * (1.0f/DD) - mu*mu;
            const float inv = rsqrtf(var + 1e-5f);
            #pragma unroll
            for (int ct = 0; ct < 4; ++ct) {
                const float hn = (acc[rt][ct][j] - mu) * inv * g1v[ct] + be1v[ct];
                const float sv = hn / (1.0f + __expf(-hn));
                Sl[R0 + lr][C0 + ct*16 + ll] = f2bf(sv);
            }
        }
    }
    __syncthreads();

    // GEMM2
    f32x4 acc2[2][4] = {};
    #pragma unroll
    for (int kt = 0; kt < 4; ++kt) {
        const v8bf a0 = *(const v8bf*)&Sl[R0 + ll][kt*32 + lg*8];
        const v8bf a1 = *(const v8bf*)&Sl[R0 + 16 + ll][kt*32 + lg*8];
        #pragma unroll
        for (int ct = 0; ct < 4; ++ct) {
            const v8bf b = *(const v8bf*)&Wp2[((kt*8 + wc*4 + ct)*64 + lane)*8];
            acc2[0][ct] = __builtin_amdgcn_mfma_f32_16x16x32_bf16(a0, b, acc2[0][ct], 0, 0, 0);
            acc2[1][ct] = __builtin_amdgcn_mfma_f32_16x16x32_bf16(a1, b, acc2[1][ct], 0, 0, 0);
        }
    }

    // residual + store
    #pragma unroll
    for (int rt = 0; rt < 2; ++rt)
        #pragma unroll
        for (int ct = 0; ct < 4; ++ct)
            #pragma unroll
            for (int j = 0; j < 4; ++j) {
                const int lr = rt*16 + lg*4 + j;
                const int col = C0 + ct*16 + ll;
                const float v = bf2f(AeE[R0 + lr][col]) + acc2[rt][ct][j] + b2v[ct];
                ePw[(base + R0 + lr)*DD + col] = f2bf(v);
                if constexpr (!L0)
                    e_out[(long)eidx[R0 + lr]*DD + col] = v;
            }
}

// ---------------------------------------------------------------------------
// Full-K edge MLP fallback (layer 1 without NG1 space)
// ---------------------------------------------------------------------------
__global__ __launch_bounds__(256, 4)
void edge_mlp_full(const unsigned short* __restrict__ e_in,
                   const float* __restrict__ nf,
                   const int* __restrict__ elist,
                   const int* __restrict__ srcA, const int* __restrict__ dstA,
                   const unsigned short* __restrict__ Wa,
                   const unsigned short* __restrict__ Wbc,
                   const float* __restrict__ b1, const float* __restrict__ g1,
                   const float* __restrict__ be1,
                   const unsigned short* __restrict__ Wp2,
                   const float* __restrict__ b2, float* __restrict__ e_out)
{
    __shared__ __align__(16) unsigned short AeE[64][136];
    __shared__ __align__(16) unsigned short AeG[64][132];
    __shared__ float red[4][32][2];
    __shared__ int eidx[64], sidx[64], didx[64];

    const int tid = threadIdx.x;
    const long base = (long)blockIdx.x * 64;

    if (tid < 64) {
        const int i = elist[base + tid];
        eidx[tid] = i; sidx[tid] = srcA[i]; didx[tid] = dstA[i];
    }

    const int lane = tid & 63, w = tid >> 6;
    const int wr = w >> 1, wc = w & 1;
    const int R0 = wr*32, C0 = wc*64;
    const int lg = lane >> 4, ll = lane & 15;

    #pragma unroll
    for (int it = 0; it < 4; ++it) {
        const int i = tid + it*256;
        const int row = i >> 4;
        const int c = (i & 15) * 8;
        *(uint4*)&AeE[row][c] = *(const uint4*)&e_in[(base + row)*DD + c];
    }
    __syncthreads();

    #pragma unroll
    for (int it = 0; it < 8; ++it) {
        const int i = tid + it*256;
        const int row = i >> 5;
        const int c = (i & 31) * 4;
        const float4 v = *(const float4*)&nf[(long)sidx[row]*DD + c];
        ushort4 o; o.x = f2bf(v.x); o.y = f2bf(v.y); o.z = f2bf(v.z); o.w = f2bf(v.w);
        *(ushort4*)&AeG[row][c] = o;
    }
    float4 dreg[8];
    #pragma unroll
    for (int it = 0; it < 8; ++it) {
        const int i = tid + it*256;
        const int row = i >> 5;
        const int c = (i & 31) * 4;
        dreg[it] = *(const float4*)&nf[(long)didx[row]*DD + c];
    }
    __syncthreads();

    float b1v[4], g1v[4], be1v[4], b2v[4];
    #pragma unroll
    for (int ct = 0; ct < 4; ++ct) {
        const int c = C0 + ct*16 + ll;
        b1v[ct] = b1[c]; g1v[ct] = g1[c]; be1v[ct] = be1[c]; b2v[ct] = b2[c];
    }

    f32x4 acc[2][4] = {};
    #pragma unroll
    for (int kt = 0; kt < 8; ++kt) {
        const unsigned short* a0p = (kt < 4) ? &AeE[R0 + ll][kt*32 + lg*8]
                                             : &AeG[R0 + ll][(kt-4)*32 + lg*8];
        const unsigned short* a1p = (kt < 4) ? &AeE[R0 + 16 + ll][kt*32 + lg*8]
                                             : &AeG[R0 + 16 + ll][(kt-4)*32 + lg*8];
        const v8bf a0 = *(const v8bf*)a0p;
        const v8bf a1 = *(const v8bf*)a1p;
        #pragma unroll
        for (int ct = 0; ct < 4; ++ct) {
            const v8bf b = (kt < 4)
                ? *(const v8bf*)&Wa[((kt*8 + wc*4 + ct)*64 + lane)*8]
                : *(const v8bf*)&Wbc[(((kt-4)*16 + wc*4 + ct)*64 + lane)*8];
            acc[0][ct] = __builtin_amdgcn_mfma_f32_16x16x32_bf16(a0, b, acc[0][ct], 0, 0, 0);
            acc[1][ct] = __builtin_amdgcn_mfma_f32_16x16x32_bf16(a1, b, acc[1][ct], 0, 0, 0);
        }
    }
    __syncthreads();

    #pragma unroll
    for (int it = 0; it < 8; ++it) {
        const int i = tid + it*256;
        const int row = i >> 5;
        const int c = (i & 31) * 4;
        ushort4 o; o.x = f2bf(dreg[it].x); o.y = f2bf(dreg[it].y);
        o.z = f2bf(dreg[it].z); o.w = f2bf(dreg[it].w);
        *(ushort4*)&AeG[row][c] = o;
    }
    __syncthreads();

    #pragma unroll
    for (int kt = 0; kt < 4; ++kt) {
        const v8bf a0 = *(const v8bf*)&AeG[R0 + ll][kt*32 + lg*8];
        const v8bf a1 = *(const v8bf*)&AeG[R0 + 16 + ll][kt*32 + lg*8];
        #pragma unroll
        for (int ct = 0; ct < 4; ++ct) {
            const v8bf b = *(const v8bf*)&Wbc[((kt*16 + 8 + wc*4 + ct)*64 + lane)*8];
            acc[0][ct] = __builtin_amdgcn_mfma_f32_16x16x32_bf16(a0, b, acc[0][ct], 0, 0, 0);
            acc[1][ct] = __builtin_amdgcn_mfma_f32_16x16x32_bf16(a1, b, acc[1][ct], 0, 0, 0);
        }
    }

    f32x4 s[2], q[2];
    #pragma unroll
    for (int rt = 0; rt < 2; ++rt) {
        #pragma unroll
        for (int ct = 0; ct < 4; ++ct) acc[rt][ct] += b1v[ct];
        s[rt] = acc[rt][0] + acc[rt][1] + acc[rt][2] + acc[rt][3];
        q[rt] = acc[rt][0]*acc[rt][0] + acc[rt][1]*acc[rt][1]
              + acc[rt][2]*acc[rt][2] + acc[rt][3]*acc[rt][3];
    }
    #pragma unroll
    for (int off = 1; off <= 8; off <<= 1) {
        #pragma unroll
        for (int rt = 0; rt < 2; ++rt)
            #pragma unroll
            for (int j = 0; j < 4; ++j) {
                s[rt][j] += __shfl_xor(s[rt][j], off);
                q[rt][j] += __shfl_xor(q[rt][j], off);
            }
    }
    if (ll == 0) {
        #pragma unroll
        for (int rt = 0; rt < 2; ++rt)
            #pragma unroll
            for (int j = 0; j < 4; ++j) {
                red[w][rt*16 + lg*4 + j][0] = s[rt][j];
                red[w][rt*16 + lg*4 + j][1] = q[rt][j];
            }
    }
    __syncthreads();

    #pragma unroll
    for (int rt = 0; rt < 2; ++rt) {
        #pragma unroll
        for (int j = 0; j < 4; ++j) {
            const int lr = rt*16 + lg*4 + j;
            const float S = red[2*wr][lr][0] + red[2*wr + 1][lr][0];
            const float Q = red[2*wr][lr][1] + red[2*wr + 1][lr][1];
            const float mu = S * (1.0f/DD);
            const float var = Q * (1.0f/DD) - mu*mu;
            const float inv = rsqrtf(var + 1e-5f);
            #pragma unroll
            for (int ct = 0; ct < 4; ++ct) {
                const float hn = (acc[rt][ct][j] - mu) * inv * g1v[ct] + be1v[ct];
                const float sv = hn / (1.0f + __expf(-hn));
                AeG[R0 + lr][C0 + ct*16 + ll] = f2bf(sv);
            }
        }
    }
    __syncthreads();

    f32x4 acc2[2][4] = {};
    #pragma unroll
    for (int kt = 0; kt < 4; ++kt) {
        const v8bf a0 = *(const v8bf*)&AeG[R0 + ll][kt*32 + lg*8];
        const v8bf a1 = *(const v8bf*)&AeG[R0 + 16 + ll][kt*32 + lg*8];
        #pragma unroll
        for (int ct = 0; ct < 4; ++ct) {
            const v8bf b = *(const v8bf*)&Wp2[((kt*8 + wc*4 + ct)*64 + lane)*8];
            acc2[0][ct] = __builtin_amdgcn_mfma_f32_16x16x32_bf16(a0, b, acc2[0][ct], 0, 0, 0);
            acc2[1][ct] = __builtin_amdgcn_mfma_f32_16x16x32_bf16(a1, b, acc2[1][ct], 0, 0, 0);
        }
    }

    #pragma unroll
    for (int rt = 0; rt < 2; ++rt)
        #pragma unroll
        for (int ct = 0; ct < 4; ++ct)
            #pragma unroll
            for (int j = 0; j < 4; ++j) {
                const int lr = rt*16 + lg*4 + j;
                const int col = C0 + ct*16 + ll;
                const float v = bf2f(AeE[R0 + lr][col]) + acc2[rt][ct][j] + b2v[ct];
                e_out[(long)eidx[R0 + lr]*DD + col] = v;
            }
}

// ---------------------------------------------------------------------------
// Node MLP with CSR gather-aggregate.
// ---------------------------------------------------------------------------
template <bool SEQ>
__global__ __launch_bounds__(256)
void node_mlp(const float* n_in, const void* __restrict__ e_buf_v,
              const int* __restrict__ off, const int* __restrict__ elist,
              const unsigned short* __restrict__ Wp1,
              const float* __restrict__ b1, const float* __restrict__ g1,
              const float* __restrict__ be1,
              const unsigned short* __restrict__ Wp2,
              const float* __restrict__ b2, float* n_out)
{
    __shared__ __align__(16) unsigned short AnN[64][136];
    __shared__ __align__(16) unsigned short AnG[64][136];
    __shared__ float red[4][32][2];

    const int tid = threadIdx.x;
    const long base = (long)blockIdx.x * 64;

    const int lane = tid & 63, w = tid >> 6;
    const int wr = w >> 1, wc = w & 1;
    const int R0 = wr*32, C0 = wc*64;
    const int lg = lane >> 4, ll = lane & 15;

    float b1v[4], g1v[4], be1v[4], b2v[4];
    #pragma unroll
    for (int ct = 0; ct < 4; ++ct) {
        const int c = C0 + ct*16 + ll;
        b1v[ct] = b1[c]; g1v[ct] = g1[c]; be1v[ct] = be1[c]; b2v[ct] = b2[c];
    }

    // gather-aggregate: 4 threads/row x 32 cols
    {
        const int r  = tid >> 2;
        const int cq = (tid & 3) * 32;
        const long row = base + r;
        float a[32];
        #pragma unroll
        for (int q = 0; q < 32; ++q) a[q] = 0.f;
        if (row < NODES) {
            const int jb = off[row], je = off[row + 1];
            for (int j = jb; j < je; ++j) {
                if constexpr (SEQ) {
                    const unsigned short* p = (const unsigned short*)e_buf_v + (long)j*DD + cq;
                    #pragma unroll
                    for (int u = 0; u < 4; ++u) {
                        const uint4 v = *(const uint4*)(p + u*8);
                        a[u*8+0] += bf2f((unsigned short)(v.x & 0xffff));
                        a[u*8+1] += bf2f((unsigned short)(v.x >> 16));
                        a[u*8+2] += bf2f((unsigned short)(v.y & 0xffff));
                        a[u*8+3] += bf2f((unsigned short)(v.y >> 16));
                        a[u*8+4] += bf2f((unsigned short)(v.z & 0xffff));
                        a[u*8+5] += bf2f((unsigned short)(v.z >> 16));
                        a[u*8+6] += bf2f((unsigned short)(v.w & 0xffff));
                        a[u*8+7] += bf2f((unsigned short)(v.w >> 16));
                    }
                } else {
                    const float* p = (const float*)e_buf_v + (long)elist[j]*DD + cq;
                    #pragma unroll
                    for (int q = 0; q < 8; ++q) {
                        const float4 v = *(const float4*)(p + q*4);
                        a[q*4+0] += v.x; a[q*4+1] += v.y;
                        a[q*4+2] += v.z; a[q*4+3] += v.w;
                    }
                }
            }
        }
        #pragma unroll
        for (int q = 0; q < 8; ++q) {
            ushort4 o;
            o.x = f2bf(a[q*4+0]); o.y = f2bf(a[q*4+1]);
            o.z = f2bf(a[q*4+2]); o.w = f2bf(a[q*4+3]);
            *(ushort4*)&AnG[r][cq + q*4] = o;
        }
    }

    #pragma unroll
    for (int it = 0; it < 8; ++it) {
        const int i = tid + it*256;
        const int row = i >> 5;
        const int c = (i & 31) * 4;
        float4 v = {0.f, 0.f, 0.f, 0.f};
        if (base + row < NODES) v = *(const float4*)&n_in[(base + row)*DD + c];
        ushort4 o; o.x = f2bf(v.x); o.y = f2bf(v.y); o.z = f2bf(v.z); o.w = f2bf(v.w);
        *(ushort4*)&AnN[row][c] = o;
    }
    __syncthreads();

    f32x4 acc[2][4] = {};
    #pragma unroll
    for (int kt = 0; kt < 8; ++kt) {
        const unsigned short* a0p = (kt < 4) ? &AnN[R0 + ll][kt*32 + lg*8]
                                             : &AnG[R0 + ll][(kt-4)*32 + lg*8];
        const unsigned short* a1p = (kt < 4) ? &AnN[R0 + 16 + ll][kt*32 + lg*8]
                                             : &AnG[R0 + 16 + ll][(kt-4)*32 + lg*8];
        const v8bf a0 = *(const v8bf*)a0p;
        const v8bf a1 = *(const v8bf*)a1p;
        #pragma unroll
        for (int ct = 0; ct < 4; ++ct) {
            const v8bf b = *(const v8bf*)&Wp1[((kt*8 + wc*4 + ct)*64 + lane)*8];
            acc[0][ct] = __builtin_amdgcn_mfma_f32_16x16x32_bf16(a0, b, acc[0][ct], 0, 0, 0);
            acc[1][ct] = __builtin_amdgcn_mfma_f32_16x16x32_bf16(a1, b, acc[1][ct], 0, 0, 0);
        }
    }

    f32x4 s[2], q2[2];
    #pragma unroll
    for (int rt = 0; rt < 2; ++rt) {
        #pragma unroll
        for (int ct = 0; ct < 4; ++ct) acc[rt][ct] += b1v[ct];
        s[rt] = acc[rt][0] + acc[rt][1] + acc[rt][2] + acc[rt][3];
        q2[rt] = acc[rt][0]*acc[rt][0] + acc[rt][1]*acc[rt][1]
               + acc[rt][2]*acc[rt][2] + acc[rt][3]*acc[rt][3];
    }
    #pragma unroll
    for (int off_ = 1; off_ <= 8; off_ <<= 1) {
        #pragma unroll
        for (int rt = 0; rt < 2; ++rt)
            #pragma unroll
            for (int j = 0; j < 4; ++j) {
                s[rt][j] += __shfl_xor(s[rt][j], off_);
                q2[rt][j] += __shfl_xor(q2[rt][j], off_);
            }
    }
    if (ll == 0) {
        #pragma unroll
        for (int rt = 0; rt < 2; ++rt)
            #pragma unroll
            for (int j = 0; j < 4; ++j) {
                red[w][rt*16 + lg*4 + j][0] = s[rt][j];
                red[w][rt*16 + lg*4 + j][1] = q2[rt][j];
            }
    }
    __syncthreads();

    #pragma unroll
    for (int rt = 0; rt < 2; ++rt) {
        #pragma unroll
        for (int j = 0; j < 4; ++j) {
            const int lr = rt*16 + lg*4 + j;
            const float S = red[2*wr][lr][0] + red[2*wr + 1][lr][0];
            const float Q = red[2*wr][lr][1] + red[2*wr + 1][lr][1];
            const float mu = S * (1.0f/DD);
            const float var = Q * (1.0f/DD) - mu*mu;
            const float inv = rsqrtf(var + 1e-5f);
            #pragma unroll
            for (int ct = 0; ct < 4; ++ct) {
                const float hn = (acc[rt][ct][j] - mu) * inv * g1v[ct] + be1v[ct];
                const float sv = hn / (1.0f + __expf(-hn));
                AnG[R0 + lr][C0 + ct*16 + ll] = f2bf(sv);
            }
        }
    }
    __syncthreads();

    f32x4 acc2[2][4] = {};
    #pragma unroll
    for (int kt = 0; kt < 4; ++kt) {
        const v8bf a0 = *(const v8bf*)&AnG[R0 + ll][kt*32 + lg*8];
        const v8bf a1 = *(const v8bf*)&AnG[R0 + 16 + ll][kt*32 + lg*8];
        #pragma unroll
        for (int ct = 0; ct < 4; ++ct) {
            const v8bf b = *(const v8bf*)&Wp2[((kt*8 + wc*4 + ct)*64 + lane)*8];
            acc2[0][ct] = __builtin_amdgcn_mfma_f32_16x16x32_bf16(a0, b, acc2[0][ct], 0, 0, 0);
            acc2[1][ct] = __builtin_amdgcn_mfma_f32_16x16x32_bf16(a1, b, acc2[1][ct], 0, 0, 0);
        }
    }

    #pragma unroll
    for (int rt = 0; rt < 2; ++rt)
        #pragma unroll
        for (int ct = 0; ct < 4; ++ct)
            #pragma unroll
            for (int j = 0; j < 4; ++j) {
                const long grow = base + R0 + rt*16 + lg*4 + j;
                if (grow < NODES) {
                    const int col = C0 + ct*16 + ll;
                    n_out[grow*DD + col] = n_in[grow*DD + col] + acc2[rt][ct][j] + b2v[ct];
                }
            }
}

extern "C" void kernel_launch(void* const* d_in, const int* in_sizes, int n_in,
                              void* d_out, int out_size, void* d_ws, size_t ws_size,
                              hipStream_t stream) {
    const float* node_feat = (const float*)d_in[0];
    const float* edge_attr = (const float*)d_in[1];
    const int*   edge_index= (const int*)d_in[2];
    const float* eW1 = (const float*)d_in[3];
    const float* eb1 = (const float*)d_in[4];
    const float* eg1 = (const float*)d_in[5];
    const float* ebe1= (const float*)d_in[6];
    const float* eW2 = (const float*)d_in[7];
    const float* eb2 = (const float*)d_in[8];
    const float* nW1 = (const float*)d_in[9];
    const float* nb1 = (const float*)d_in[10];
    const float* ng1 = (const float*)d_in[11];
    const float* nbe1= (const float*)d_in[12];
    const float* nW2 = (const float*)d_in[13];
    const float* nb2 = (const float*)d_in[14];

    const int N = NODES, E = EDGES;
    const int* src  = edge_index;
    const int* dstI = edge_index + E;

    float* out_n = (float*)d_out;
    float* out_e = (float*)d_out + (size_t)N * DD;

    // ws: [wp 458752 B]
    //     [ints @458752: deg 50000 | off 50001 | cursor 50000 | elist 256000 |
    //                    bsum 64 | bbase 64]
    //     [e1w 65.536 MB bf16 @ 2083840]
    //     [NG1 25.6  MB bf16 @ 67619840, if ws allows]
    unsigned short* wp = (unsigned short*)d_ws;
    int* ib     = (int*)((char*)d_ws + 458752);
    int* deg    = ib;
    int* off    = ib + 50000;
    int* cursor = ib + 100001;
    int* elist  = ib + 150001;
    int* bsum   = ib + 406001;
    int* bbase  = ib + 406065;
    unsigned short* e1w = (unsigned short*)((char*)d_ws + 2083840);
    unsigned short* NG1 = (unsigned short*)((char*)d_ws + 67619840);
    const bool big_ws = ws_size >= (67619840ull + (size_t)NODES*256*2 + 64);

    pack_weights<<<48, 512, 0, stream>>>(eW1, eW2, nW1, nW2, wp);

    hipMemsetAsync(deg, 0, (size_t)N * sizeof(int), stream);
    hist_kernel<<<(E + 255)/256, 256, 0, stream>>>(dstI, deg);
    scan_pass1<<<SCAN_BLOCKS, 256, 0, stream>>>(deg, bsum);
    scan_pass2<<<1, 64, 0, stream>>>(bsum, bbase);
    scan_pass3<<<SCAN_BLOCKS, 256, 0, stream>>>(deg, bbase, off, cursor);
    place_kernel<<<(E + 255)/256, 256, 0, stream>>>(dstI, cursor, elist);

    const int NB = (N + 63)/64;
    unsigned short* NG0 = (unsigned short*)out_e;   // dead space during layer 0

    // ---- layer 0 ----
    node_proj<<<NB, 256, 0, stream>>>(node_feat, wp + 32768, NG0);
    edge_mlp_ng<true><<<E/64, 256, 0, stream>>>(
        edge_attr, NG0, elist, src, dstI,
        wp, eb1, eg1, ebe1, wp + 98304, eb2, e1w, nullptr);
    node_mlp<true><<<NB, 256, 0, stream>>>(
        node_feat, e1w, off, elist,
        wp + 131072, nb1, ng1, nbe1, wp + 196608, nb2, out_n);

    // ---- layer 1 ----
    if (big_ws) {
        node_proj<<<NB, 256, 0, stream>>>(out_n, wp + 32768 + 32768, NG1);
        edge_mlp_ng<false><<<E/64, 256, 0, stream>>>(
            e1w, NG1, elist, src, dstI,
            wp + 16384, eb1 + DD, eg1 + DD, ebe1 + DD,
            wp + 98304 + 16384, eb2 + DD, e1w /*in-place e2w*/, out_e);
        node_mlp<true><<<NB, 256, 0, stream>>>(
            out_n, e1w, off, elist,
            wp + 131072 + 32768, nb1 + DD, ng1 + DD, nbe1 + DD,
            wp + 196608 + 16384, nb2 + DD, out_n);
    } else {
        edge_mlp_full<<<E/64, 256, 0, stream>>>(
            e1w, out_n, elist, src, dstI,
            wp + 16384, wp + 32768 + 32768,
            eb1 + DD, eg1 + DD, ebe1 + DD,
            wp + 98304 + 16384, eb2 + DD, out_e);
        node_mlp<false><<<NB, 256, 0, stream>>>(
            out_n, out_e, off, elist,
            wp + 131072 + 32768, nb1 + DD, ng1 + DD, nbe1 + DD,
            wp + 196608 + 16384, nb2 + DD, out_n);
    }
}

// Round 9
// 354.278 us; speedup vs baseline: 1.0482x; 1.0482x over previous
//
#include <hip/hip_runtime.h>
#include <hip/hip_bf16.h>

typedef float f32x4 __attribute__((ext_vector_type(4)));
typedef __bf16 v8bf __attribute__((ext_vector_type(8)));

#define DD 128
#define EDGES 256000
#define NODES 50000
#define SCAN_BLOCKS 49   // 49*1024 >= 50000

__device__ __forceinline__ unsigned short f2bf(float f) {
    union { float f; unsigned u; } v; v.f = f;
    unsigned r = v.u + 0x7fffu + ((v.u >> 16) & 1u);
    return (unsigned short)(r >> 16);
}
__device__ __forceinline__ float bf2f(unsigned short u) {
    union { unsigned u; float f; } v; v.u = ((unsigned)u) << 16; return v.f;
}

// ---------------------------------------------------------------------------
// Weight prep. Packed B-fragment layout for a [K x C] matrix:
//   dst[((kt*(C/16)+ct)*64+l)*8+j] = bf16(W[(kt*32+(l>>4)*8+j)*C + ct*16+(l&15)])
// wp layout (ushorts):
//   eW1a: layer*16384 | eWbc: 32768+layer*32768 | eW2: 98304+layer*16384
//   nW1: 131072+layer*32768 | nW2: 196608+layer*16384
// ---------------------------------------------------------------------------
__global__ __launch_bounds__(512)
void pack_weights(const float* __restrict__ eW1, const float* __restrict__ eW2,
                  const float* __restrict__ nW1, const float* __restrict__ nW2,
                  unsigned short* __restrict__ wp)
{
    const int b = blockIdx.x;            // 0..47
    const int layer = b / 24;
    const int u = b % 24;
    const int t = threadIdx.x;
    const int ct0 = t >> 6, l = t & 63;
    const int lg = l >> 4, ll = l & 15;

    if (u < 8 && u >= 4) {
        // eWbc: [128 x 256], Wbc[k][c] = eW1[128 + k + (c>=128?128:0)][c&127]
        const int kt = u - 4;
        const float* W = eW1 + layer*49152;
        unsigned short* dst = wp + 32768 + layer*32768;
        #pragma unroll
        for (int h = 0; h < 2; ++h) {
            const int ct = ct0 + h*8;
            #pragma unroll
            for (int j = 0; j < 8; ++j) {
                const int k = kt*32 + lg*8 + j;
                const int cout = ct*16 + ll;
                const int row = 128 + k + ((cout >= 128) ? 128 : 0);
                const int col = cout & 127;
                dst[((kt*16 + ct)*64 + l)*8 + j] = f2bf(W[row*128 + col]);
            }
        }
        return;
    }
    const float* W; int kt; unsigned short* dst;
    if (u < 4)       { W = eW1 + layer*49152; kt = u;      dst = wp + layer*16384; }
    else if (u < 12) { W = eW2 + layer*16384; kt = u - 8;  dst = wp + 98304 + layer*16384; }
    else if (u < 20) { W = nW1 + layer*32768; kt = u - 12; dst = wp + 131072 + layer*32768; }
    else             { W = nW2 + layer*16384; kt = u - 20; dst = wp + 196608 + layer*16384; }
    #pragma unroll
    for (int j = 0; j < 8; ++j) {
        const int k = kt*32 + lg*8 + j;
        const int c = ct0*16 + ll;
        dst[((kt*8 + ct0)*64 + l)*8 + j] = f2bf(W[k*128 + c]);
    }
}

// ---------------------------------------------------------------------------
// CSR build: histogram -> 3-pass multi-block scan -> placement
// ---------------------------------------------------------------------------
__global__ void hist_kernel(const int* __restrict__ dst, int* __restrict__ deg)
{
    const int i = blockIdx.x * blockDim.x + threadIdx.x;
    if (i < EDGES) atomicAdd(&deg[dst[i]], 1);
}

__global__ __launch_bounds__(256)
void scan_pass1(const int* __restrict__ deg, int* __restrict__ bsum)
{
    __shared__ int ws[256];
    const int b = blockIdx.x, t = threadIdx.x;
    const int base = b*1024 + t*4;
    int s = 0;
    #pragma unroll
    for (int k = 0; k < 4; ++k) {
        const int idx = base + k;
        if (idx < NODES) s += deg[idx];
    }
    ws[t] = s;
    __syncthreads();
    for (int d = 128; d >= 1; d >>= 1) {
        if (t < d) ws[t] += ws[t + d];
        __syncthreads();
    }
    if (t == 0) bsum[b] = ws[0];
}

__global__ __launch_bounds__(64)
void scan_pass2(const int* __restrict__ bsum, int* __restrict__ bbase)
{
    const int t = threadIdx.x;
    const int mine = (t < SCAN_BLOCKS) ? bsum[t] : 0;
    int v = mine;
    #pragma unroll
    for (int d = 1; d < 64; d <<= 1) {
        const int u = __shfl_up(v, d);
        if (t >= d) v += u;
    }
    if (t < SCAN_BLOCKS) bbase[t] = v - mine;   // exclusive
}

__global__ __launch_bounds__(256)
void scan_pass3(const int* __restrict__ deg, const int* __restrict__ bbase,
                int* __restrict__ off, int* __restrict__ cursor)
{
    __shared__ int ws[256];
    const int b = blockIdx.x, t = threadIdx.x;
    const int base = b*1024 + t*4;
    int d4[4]; int s = 0;
    #pragma unroll
    for (int k = 0; k < 4; ++k) {
        const int idx = base + k;
        d4[k] = (idx < NODES) ? deg[idx] : 0;
        s += d4[k];
    }
    ws[t] = s;
    __syncthreads();
    for (int d = 1; d < 256; d <<= 1) {
        const int u = (t >= d) ? ws[t - d] : 0;
        __syncthreads();
        ws[t] += u;
        __syncthreads();
    }
    int run = bbase[b] + ws[t] - s;   // exclusive prefix for this thread's chunk
    #pragma unroll
    for (int k = 0; k < 4; ++k) {
        const int idx = base + k;
        if (idx < NODES) { off[idx] = run; cursor[idx] = run; run += d4[k]; }
    }
    if (b == 0 && t == 0) off[NODES] = EDGES;
}

__global__ void place_kernel(const int* __restrict__ dst, int* __restrict__ cursor,
                             int* __restrict__ elist)
{
    const int i = blockIdx.x * blockDim.x + threadIdx.x;
    if (i < EDGES) {
        const int p = atomicAdd(&cursor[dst[i]], 1);
        elist[p] = i;
    }
}

// ---------------------------------------------------------------------------
// Node projection: NG[v] = bf16(n[v] @ Wbc) in wave-contiguous fragment order:
//   flat(col) with col in [0,256): side = col>=128, cE = col&127,
//   wcE = (cE>>6)&1, ctE = (cE>>4)&3, llE = cE&15
//   NG[v*256 + side*128 + wcE*64 + llE*4 + ctE]
// Edge kernel: one ushort4/lane/(row,side); a wave covers 128 B contiguous.
// ---------------------------------------------------------------------------
__global__ __launch_bounds__(256)
void node_proj(const float* __restrict__ n,
               const unsigned short* __restrict__ Wbc,
               unsigned short* __restrict__ NG)
{
    __shared__ __align__(16) unsigned short A[64][136];
    const int tid = threadIdx.x;
    const long base = (long)blockIdx.x * 64;

    #pragma unroll
    for (int it = 0; it < 8; ++it) {
        const int i = tid + it*256;
        const int row = i >> 5;
        const int c = (i & 31) * 4;
        float4 v = {0.f, 0.f, 0.f, 0.f};
        if (base + row < NODES) v = *(const float4*)&n[(base + row)*DD + c];
        ushort4 o; o.x = f2bf(v.x); o.y = f2bf(v.y); o.z = f2bf(v.z); o.w = f2bf(v.w);
        *(ushort4*)&A[row][c] = o;
    }
    __syncthreads();

    const int lane = tid & 63, w = tid >> 6;
    const int wr = w >> 1, wc = w & 1;   // wc selects side (cols 0-127 vs 128-255)
    const int R0 = wr*32;
    const int lg = lane >> 4, ll = lane & 15;

    f32x4 acc[2][8] = {};
    #pragma unroll
    for (int kt = 0; kt < 4; ++kt) {
        const v8bf a0 = *(const v8bf*)&A[R0 + ll][kt*32 + lg*8];
        const v8bf a1 = *(const v8bf*)&A[R0 + 16 + ll][kt*32 + lg*8];
        #pragma unroll
        for (int ct = 0; ct < 8; ++ct) {
            const v8bf b = *(const v8bf*)&Wbc[((kt*16 + wc*8 + ct)*64 + lane)*8];
            acc[0][ct] = __builtin_amdgcn_mfma_f32_16x16x32_bf16(a0, b, acc[0][ct], 0, 0, 0);
            acc[1][ct] = __builtin_amdgcn_mfma_f32_16x16x32_bf16(a1, b, acc[1][ct], 0, 0, 0);
        }
    }

    // value (wc, ct_np, ll) = col wc*128 + ct_np*16 + ll
    //   -> flat = wc*128 + (ct_np>=4)*64 + ll*4 + (ct_np&3)
    #pragma unroll
    for (int rt = 0; rt < 2; ++rt)
        #pragma unroll
        for (int j = 0; j < 4; ++j) {
            const long grow = base + R0 + rt*16 + lg*4 + j;
            if (grow < NODES) {
                ushort4 o0, o1;
                o0.x = f2bf(acc[rt][0][j]); o0.y = f2bf(acc[rt][1][j]);
                o0.z = f2bf(acc[rt][2][j]); o0.w = f2bf(acc[rt][3][j]);
                o1.x = f2bf(acc[rt][4][j]); o1.y = f2bf(acc[rt][5][j]);
                o1.z = f2bf(acc[rt][6][j]); o1.w = f2bf(acc[rt][7][j]);
                *(ushort4*)&NG[grow*256 + wc*128 + ll*4]      = o0;
                *(ushort4*)&NG[grow*256 + wc*128 + 64 + ll*4] = o1;
            }
        }
}

// ---------------------------------------------------------------------------
// Edge MLP with precomputed node projections (dst-sorted edge order).
// NG reads: one ushort4 per lane per (row, side); wave-contiguous 128 B.
// ---------------------------------------------------------------------------
template <bool L0>
__global__ __launch_bounds__(256, 4)
void edge_mlp_ng(const void* __restrict__ e_in_v,
                 const unsigned short* __restrict__ NG,
                 const int* __restrict__ elist,
                 const int* __restrict__ srcA, const int* __restrict__ dstA,
                 const unsigned short* __restrict__ Wa,
                 const float* __restrict__ b1, const float* __restrict__ g1,
                 const float* __restrict__ be1,
                 const unsigned short* __restrict__ Wp2,
                 const float* __restrict__ b2,
                 unsigned short* __restrict__ ePw,
                 float* __restrict__ e_out)
{
    __shared__ __align__(16) unsigned short AeE[64][136];
    __shared__ __align__(16) unsigned short Sl[64][136];
    __shared__ float red[4][32][2];
    __shared__ int eidx[64], sidx[64], didx[64];

    const int tid = threadIdx.x;
    const long base = (long)blockIdx.x * 64;

    if (tid < 64) {
        const int i = elist[base + tid];
        eidx[tid] = i; sidx[tid] = srcA[i]; didx[tid] = dstA[i];
    }
    __syncthreads();

    const int lane = tid & 63, w = tid >> 6;
    const int wr = w >> 1, wc = w & 1;
    const int R0 = wr*32, C0 = wc*64;
    const int lg = lane >> 4, ll = lane & 15;

    // prefetch NG fragments (latency hides under staging + GEMM1a)
    ushort4 ngs[2][4], ngd[2][4];
    #pragma unroll
    for (int rt = 0; rt < 2; ++rt)
        #pragma unroll
        for (int j = 0; j < 4; ++j) {
            const int lr = rt*16 + lg*4 + j;
            const long sid = sidx[R0 + lr];
            const long did = didx[R0 + lr];
            ngs[rt][j] = *(const ushort4*)&NG[sid*256 + wc*64 + ll*4];
            ngd[rt][j] = *(const ushort4*)&NG[did*256 + 128 + wc*64 + ll*4];
        }

    // stage e tile
    if constexpr (L0) {
        const float* e_in = (const float*)e_in_v;
        #pragma unroll
        for (int it = 0; it < 8; ++it) {
            const int i = tid + it*256;
            const int row = i >> 5;
            const int c = (i & 31) * 4;
            const float4 v = *(const float4*)&e_in[(long)eidx[row]*DD + c];
            ushort4 o; o.x = f2bf(v.x); o.y = f2bf(v.y); o.z = f2bf(v.z); o.w = f2bf(v.w);
            *(ushort4*)&AeE[row][c] = o;
        }
    } else {
        const unsigned short* e_in = (const unsigned short*)e_in_v;
        #pragma unroll
        for (int it = 0; it < 4; ++it) {
            const int i = tid + it*256;
            const int row = i >> 4;
            const int c = (i & 15) * 8;
            *(uint4*)&AeE[row][c] = *(const uint4*)&e_in[(base + row)*DD + c];
        }
    }
    __syncthreads();

    float b1v[4], g1v[4], be1v[4], b2v[4];
    #pragma unroll
    for (int ct = 0; ct < 4; ++ct) {
        const int c = C0 + ct*16 + ll;
        b1v[ct] = b1[c]; g1v[ct] = g1[c]; be1v[ct] = be1[c]; b2v[ct] = b2[c];
    }

    // GEMM1a: eP @ W1a (K=128)
    f32x4 acc[2][4] = {};
    #pragma unroll
    for (int kt = 0; kt < 4; ++kt) {
        const v8bf a0 = *(const v8bf*)&AeE[R0 + ll][kt*32 + lg*8];
        const v8bf a1 = *(const v8bf*)&AeE[R0 + 16 + ll][kt*32 + lg*8];
        #pragma unroll
        for (int ct = 0; ct < 4; ++ct) {
            const v8bf b = *(const v8bf*)&Wa[((kt*8 + wc*4 + ct)*64 + lane)*8];
            acc[0][ct] = __builtin_amdgcn_mfma_f32_16x16x32_bf16(a0, b, acc[0][ct], 0, 0, 0);
            acc[1][ct] = __builtin_amdgcn_mfma_f32_16x16x32_bf16(a1, b, acc[1][ct], 0, 0, 0);
        }
    }

    // + NG[src] + NG[dst] from prefetched registers
    #pragma unroll
    for (int rt = 0; rt < 2; ++rt)
        #pragma unroll
        for (int j = 0; j < 4; ++j) {
            const unsigned short* ps = (const unsigned short*)&ngs[rt][j];
            const unsigned short* pd = (const unsigned short*)&ngd[rt][j];
            #pragma unroll
            for (int ct = 0; ct < 4; ++ct)
                acc[rt][ct][j] += bf2f(ps[ct]) + bf2f(pd[ct]);
        }

    // bias + LN stats
    f32x4 s[2], q[2];
    #pragma unroll
    for (int rt = 0; rt < 2; ++rt) {
        #pragma unroll
        for (int ct = 0; ct < 4; ++ct) acc[rt][ct] += b1v[ct];
        s[rt] = acc[rt][0] + acc[rt][1] + acc[rt][2] + acc[rt][3];
        q[rt] = acc[rt][0]*acc[rt][0] + acc[rt][1]*acc[rt][1]
              + acc[rt][2]*acc[rt][2] + acc[rt][3]*acc[rt][3];
    }
    #pragma unroll
    for (int off = 1; off <= 8; off <<= 1) {
        #pragma unroll
        for (int rt = 0; rt < 2; ++rt)
            #pragma unroll
            for (int j = 0; j < 4; ++j) {
                s[rt][j] += __shfl_xor(s[rt][j], off);
                q[rt][j] += __shfl_xor(q[rt][j], off);
            }
    }
    if (ll == 0) {
        #pragma unroll
        for (int rt = 0; rt < 2; ++rt)
            #pragma unroll
            for (int j = 0; j < 4; ++j) {
                red[w][rt*16 + lg*4 + j][0] = s[rt][j];
                red[w][rt*16 + lg*4 + j][1] = q[rt][j];
            }
    }
    __syncthreads();

    // LN + SiLU -> Sl
    #pragma unroll
    for (int rt = 0; rt < 2; ++rt) {
        #pragma unroll
        for (int j = 0; j < 4; ++j) {
            const int lr = rt*16 + lg*4 + j;
            const float S = red[2*wr][lr][0] + red[2*wr + 1][lr][0];
            const float Q = red[2*wr][lr][1] + red[2*wr + 1][lr][1];
            const float mu = S * (1.0f/DD);
            const float var = Q * (1.0f/DD) - mu*mu;
            const float inv = rsqrtf(var + 1e-5f);
            #pragma unroll
            for (int ct = 0; ct < 4; ++ct) {
                const float hn = (acc[rt][ct][j] - mu) * inv * g1v[ct] + be1v[ct];
                const float sv = hn / (1.0f + __expf(-hn));
                Sl[R0 + lr][C0 + ct*16 + ll] = f2bf(sv);
            }
        }
    }
    __syncthreads();

    // GEMM2
    f32x4 acc2[2][4] = {};
    #pragma unroll
    for (int kt = 0; kt < 4; ++kt) {
        const v8bf a0 = *(const v8bf*)&Sl[R0 + ll][kt*32 + lg*8];
        const v8bf a1 = *(const v8bf*)&Sl[R0 + 16 + ll][kt*32 + lg*8];
        #pragma unroll
        for (int ct = 0; ct < 4; ++ct) {
            const v8bf b = *(const v8bf*)&Wp2[((kt*8 + wc*4 + ct)*64 + lane)*8];
            acc2[0][ct] = __builtin_amdgcn_mfma_f32_16x16x32_bf16(a0, b, acc2[0][ct], 0, 0, 0);
            acc2[1][ct] = __builtin_amdgcn_mfma_f32_16x16x32_bf16(a1, b, acc2[1][ct], 0, 0, 0);
        }
    }

    // residual + store
    #pragma unroll
    for (int rt = 0; rt < 2; ++rt)
        #pragma unroll
        for (int ct = 0; ct < 4; ++ct)
            #pragma unroll
            for (int j = 0; j < 4; ++j) {
                const int lr = rt*16 + lg*4 + j;
                const int col = C0 + ct*16 + ll;
                const float v = bf2f(AeE[R0 + lr][col]) + acc2[rt][ct][j] + b2v[ct];
                ePw[(base + R0 + lr)*DD + col] = f2bf(v);
                if constexpr (!L0)
                    e_out[(long)eidx[R0 + lr]*DD + col] = v;
            }
}

// ---------------------------------------------------------------------------
// Full-K edge MLP fallback (layer 1 without NG1 space)
// ---------------------------------------------------------------------------
__global__ __launch_bounds__(256, 4)
void edge_mlp_full(const unsigned short* __restrict__ e_in,
                   const float* __restrict__ nf,
                   const int* __restrict__ elist,
                   const int* __restrict__ srcA, const int* __restrict__ dstA,
                   const unsigned short* __restrict__ Wa,
                   const unsigned short* __restrict__ Wbc,
                   const float* __restrict__ b1, const float* __restrict__ g1,
                   const float* __restrict__ be1,
                   const unsigned short* __restrict__ Wp2,
                   const float* __restrict__ b2, float* __restrict__ e_out)
{
    __shared__ __align__(16) unsigned short AeE[64][136];
    __shared__ __align__(16) unsigned short AeG[64][132];
    __shared__ float red[4][32][2];
    __shared__ int eidx[64], sidx[64], didx[64];

    const int tid = threadIdx.x;
    const long base = (long)blockIdx.x * 64;

    if (tid < 64) {
        const int i = elist[base + tid];
        eidx[tid] = i; sidx[tid] = srcA[i]; didx[tid] = dstA[i];
    }

    const int lane = tid & 63, w = tid >> 6;
    const int wr = w >> 1, wc = w & 1;
    const int R0 = wr*32, C0 = wc*64;
    const int lg = lane >> 4, ll = lane & 15;

    #pragma unroll
    for (int it = 0; it < 4; ++it) {
        const int i = tid + it*256;
        const int row = i >> 4;
        const int c = (i & 15) * 8;
        *(uint4*)&AeE[row][c] = *(const uint4*)&e_in[(base + row)*DD + c];
    }
    __syncthreads();

    #pragma unroll
    for (int it = 0; it < 8; ++it) {
        const int i = tid + it*256;
        const int row = i >> 5;
        const int c = (i & 31) * 4;
        const float4 v = *(const float4*)&nf[(long)sidx[row]*DD + c];
        ushort4 o; o.x = f2bf(v.x); o.y = f2bf(v.y); o.z = f2bf(v.z); o.w = f2bf(v.w);
        *(ushort4*)&AeG[row][c] = o;
    }
    float4 dreg[8];
    #pragma unroll
    for (int it = 0; it < 8; ++it) {
        const int i = tid + it*256;
        const int row = i >> 5;
        const int c = (i & 31) * 4;
        dreg[it] = *(const float4*)&nf[(long)didx[row]*DD + c];
    }
    __syncthreads();

    float b1v[4], g1v[4], be1v[4], b2v[4];
    #pragma unroll
    for (int ct = 0; ct < 4; ++ct) {
        const int c = C0 + ct*16 + ll;
        b1v[ct] = b1[c]; g1v[ct] = g1[c]; be1v[ct] = be1[c]; b2v[ct] = b2[c];
    }

    f32x4 acc[2][4] = {};
    #pragma unroll
    for (int kt = 0; kt < 8; ++kt) {
        const unsigned short* a0p = (kt < 4) ? &AeE[R0 + ll][kt*32 + lg*8]
                                             : &AeG[R0 + ll][(kt-4)*32 + lg*8];
        const unsigned short* a1p = (kt < 4) ? &AeE[R0 + 16 + ll][kt*32 + lg*8]
                                             : &AeG[R0 + 16 + ll][(kt-4)*32 + lg*8];
        const v8bf a0 = *(const v8bf*)a0p;
        const v8bf a1 = *(const v8bf*)a1p;
        #pragma unroll
        for (int ct = 0; ct < 4; ++ct) {
            const v8bf b = (kt < 4)
                ? *(const v8bf*)&Wa[((kt*8 + wc*4 + ct)*64 + lane)*8]
                : *(const v8bf*)&Wbc[(((kt-4)*16 + wc*4 + ct)*64 + lane)*8];
            acc[0][ct] = __builtin_amdgcn_mfma_f32_16x16x32_bf16(a0, b, acc[0][ct], 0, 0, 0);
            acc[1][ct] = __builtin_amdgcn_mfma_f32_16x16x32_bf16(a1, b, acc[1][ct], 0, 0, 0);
        }
    }
    __syncthreads();

    #pragma unroll
    for (int it = 0; it < 8; ++it) {
        const int i = tid + it*256;
        const int row = i >> 5;
        const int c = (i & 31) * 4;
        ushort4 o; o.x = f2bf(dreg[it].x); o.y = f2bf(dreg[it].y);
        o.z = f2bf(dreg[it].z); o.w = f2bf(dreg[it].w);
        *(ushort4*)&AeG[row][c] = o;
    }
    __syncthreads();

    #pragma unroll
    for (int kt = 0; kt < 4; ++kt) {
        const v8bf a0 = *(const v8bf*)&AeG[R0 + ll][kt*32 + lg*8];
        const v8bf a1 = *(const v8bf*)&AeG[R0 + 16 + ll][kt*32 + lg*8];
        #pragma unroll
        for (int ct = 0; ct < 4; ++ct) {
            const v8bf b = *(const v8bf*)&Wbc[((kt*16 + 8 + wc*4 + ct)*64 + lane)*8];
            acc[0][ct] = __builtin_amdgcn_mfma_f32_16x16x32_bf16(a0, b, acc[0][ct], 0, 0, 0);
            acc[1][ct] = __builtin_amdgcn_mfma_f32_16x16x32_bf16(a1, b, acc[1][ct], 0, 0, 0);
        }
    }

    f32x4 s[2], q[2];
    #pragma unroll
    for (int rt = 0; rt < 2; ++rt) {
        #pragma unroll
        for (int ct = 0; ct < 4; ++ct) acc[rt][ct] += b1v[ct];
        s[rt] = acc[rt][0] + acc[rt][1] + acc[rt][2] + acc[rt][3];
        q[rt] = acc[rt][0]*acc[rt][0] + acc[rt][1]*acc[rt][1]
              + acc[rt][2]*acc[rt][2] + acc[rt][3]*acc[rt][3];
    }
    #pragma unroll
    for (int off = 1; off <= 8; off <<= 1) {
        #pragma unroll
        for (int rt = 0; rt < 2; ++rt)
            #pragma unroll
            for (int j = 0; j < 4; ++j) {
                s[rt][j] += __shfl_xor(s[rt][j], off);
                q[rt][j] += __shfl_xor(q[rt][j], off);
            }
    }
    if (ll == 0) {
        #pragma unroll
        for (int rt = 0; rt < 2; ++rt)
            #pragma unroll
            for (int j = 0; j < 4; ++j) {
                red[w][rt*16 + lg*4 + j][0] = s[rt][j];
                red[w][rt*16 + lg*4 + j][1] = q[rt][j];
            }
    }
    __syncthreads();

    #pragma unroll
    for (int rt = 0; rt < 2; ++rt) {
        #pragma unroll
        for (int j = 0; j < 4; ++j) {
            const int lr = rt*16 + lg*4 + j;
            const float S = red[2*wr][lr][0] + red[2*wr + 1][lr][0];
            const float Q = red[2*wr][lr][1] + red[2*wr + 1][lr][1];
            const float mu = S * (1.0f/DD);
            const float var = Q * (1.0f/DD) - mu*mu;
            const float inv = rsqrtf(var + 1e-5f);
            #pragma unroll
            for (int ct = 0; ct < 4; ++ct) {
                const float hn = (acc[rt][ct][j] - mu) * inv * g1v[ct] + be1v[ct];
                const float sv = hn / (1.0f + __expf(-hn));
                AeG[R0 + lr][C0 + ct*16 + ll] = f2bf(sv);
            }
        }
    }
    __syncthreads();

    f32x4 acc2[2][4] = {};
    #pragma unroll
    for (int kt = 0; kt < 4; ++kt) {
        const v8bf a0 = *(const v8bf*)&AeG[R0 + ll][kt*32 + lg*8];
        const v8bf a1 = *(const v8bf*)&AeG[R0 + 16 + ll][kt*32 + lg*8];
        #pragma unroll
        for (int ct = 0; ct < 4; ++ct) {
            const v8bf b = *(const v8bf*)&Wp2[((kt*8 + wc*4 + ct)*64 + lane)*8];
            acc2[0][ct] = __builtin_amdgcn_mfma_f32_16x16x32_bf16(a0, b, acc2[0][ct], 0, 0, 0);
            acc2[1][ct] = __builtin_amdgcn_mfma_f32_16x16x32_bf16(a1, b, acc2[1][ct], 0, 0, 0);
        }
    }

    #pragma unroll
    for (int rt = 0; rt < 2; ++rt)
        #pragma unroll
        for (int ct = 0; ct < 4; ++ct)
            #pragma unroll
            for (int j = 0; j < 4; ++j) {
                const int lr = rt*16 + lg*4 + j;
                const int col = C0 + ct*16 + ll;
                const float v = bf2f(AeE[R0 + lr][col]) + acc2[rt][ct][j] + b2v[ct];
                e_out[(long)eidx[R0 + lr]*DD + col] = v;
            }
}

// ---------------------------------------------------------------------------
// Node MLP with CSR gather-aggregate.
// ---------------------------------------------------------------------------
template <bool SEQ>
__global__ __launch_bounds__(256)
void node_mlp(const float* n_in, const void* __restrict__ e_buf_v,
              const int* __restrict__ off, const int* __restrict__ elist,
              const unsigned short* __restrict__ Wp1,
              const float* __restrict__ b1, const float* __restrict__ g1,
              const float* __restrict__ be1,
              const unsigned short* __restrict__ Wp2,
              const float* __restrict__ b2, float* n_out)
{
    __shared__ __align__(16) unsigned short AnN[64][136];
    __shared__ __align__(16) unsigned short AnG[64][136];
    __shared__ float red[4][32][2];

    const int tid = threadIdx.x;
    const long base = (long)blockIdx.x * 64;

    const int lane = tid & 63, w = tid >> 6;
    const int wr = w >> 1, wc = w & 1;
    const int R0 = wr*32, C0 = wc*64;
    const int lg = lane >> 4, ll = lane & 15;

    float b1v[4], g1v[4], be1v[4], b2v[4];
    #pragma unroll
    for (int ct = 0; ct < 4; ++ct) {
        const int c = C0 + ct*16 + ll;
        b1v[ct] = b1[c]; g1v[ct] = g1[c]; be1v[ct] = be1[c]; b2v[ct] = b2[c];
    }

    // gather-aggregate: 4 threads/row x 32 cols
    {
        const int r  = tid >> 2;
        const int cq = (tid & 3) * 32;
        const long row = base + r;
        float a[32];
        #pragma unroll
        for (int q = 0; q < 32; ++q) a[q] = 0.f;
        if (row < NODES) {
            const int jb = off[row], je = off[row + 1];
            for (int j = jb; j < je; ++j) {
                if constexpr (SEQ) {
                    const unsigned short* p = (const unsigned short*)e_buf_v + (long)j*DD + cq;
                    #pragma unroll
                    for (int u = 0; u < 4; ++u) {
                        const uint4 v = *(const uint4*)(p + u*8);
                        a[u*8+0] += bf2f((unsigned short)(v.x & 0xffff));
                        a[u*8+1] += bf2f((unsigned short)(v.x >> 16));
                        a[u*8+2] += bf2f((unsigned short)(v.y & 0xffff));
                        a[u*8+3] += bf2f((unsigned short)(v.y >> 16));
                        a[u*8+4] += bf2f((unsigned short)(v.z & 0xffff));
                        a[u*8+5] += bf2f((unsigned short)(v.z >> 16));
                        a[u*8+6] += bf2f((unsigned short)(v.w & 0xffff));
                        a[u*8+7] += bf2f((unsigned short)(v.w >> 16));
                    }
                } else {
                    const float* p = (const float*)e_buf_v + (long)elist[j]*DD + cq;
                    #pragma unroll
                    for (int q = 0; q < 8; ++q) {
                        const float4 v = *(const float4*)(p + q*4);
                        a[q*4+0] += v.x; a[q*4+1] += v.y;
                        a[q*4+2] += v.z; a[q*4+3] += v.w;
                    }
                }
            }
        }
        #pragma unroll
        for (int q = 0; q < 8; ++q) {
            ushort4 o;
            o.x = f2bf(a[q*4+0]); o.y = f2bf(a[q*4+1]);
            o.z = f2bf(a[q*4+2]); o.w = f2bf(a[q*4+3]);
            *(ushort4*)&AnG[r][cq + q*4] = o;
        }
    }

    #pragma unroll
    for (int it = 0; it < 8; ++it) {
        const int i = tid + it*256;
        const int row = i >> 5;
        const int c = (i & 31) * 4;
        float4 v = {0.f, 0.f, 0.f, 0.f};
        if (base + row < NODES) v = *(const float4*)&n_in[(base + row)*DD + c];
        ushort4 o; o.x = f2bf(v.x); o.y = f2bf(v.y); o.z = f2bf(v.z); o.w = f2bf(v.w);
        *(ushort4*)&AnN[row][c] = o;
    }
    __syncthreads();

    f32x4 acc[2][4] = {};
    #pragma unroll
    for (int kt = 0; kt < 8; ++kt) {
        const unsigned short* a0p = (kt < 4) ? &AnN[R0 + ll][kt*32 + lg*8]
                                             : &AnG[R0 + ll][(kt-4)*32 + lg*8];
        const unsigned short* a1p = (kt < 4) ? &AnN[R0 + 16 + ll][kt*32 + lg*8]
                                             : &AnG[R0 + 16 + ll][(kt-4)*32 + lg*8];
        const v8bf a0 = *(const v8bf*)a0p;
        const v8bf a1 = *(const v8bf*)a1p;
        #pragma unroll
        for (int ct = 0; ct < 4; ++ct) {
            const v8bf b = *(const v8bf*)&Wp1[((kt*8 + wc*4 + ct)*64 + lane)*8];
            acc[0][ct] = __builtin_amdgcn_mfma_f32_16x16x32_bf16(a0, b, acc[0][ct], 0, 0, 0);
            acc[1][ct] = __builtin_amdgcn_mfma_f32_16x16x32_bf16(a1, b, acc[1][ct], 0, 0, 0);
        }
    }

    f32x4 s[2], q2[2];
    #pragma unroll
    for (int rt = 0; rt < 2; ++rt) {
        #pragma unroll
        for (int ct = 0; ct < 4; ++ct) acc[rt][ct] += b1v[ct];
        s[rt] = acc[rt][0] + acc[rt][1] + acc[rt][2] + acc[rt][3];
        q2[rt] = acc[rt][0]*acc[rt][0] + acc[rt][1]*acc[rt][1]
               + acc[rt][2]*acc[rt][2] + acc[rt][3]*acc[rt][3];
    }
    #pragma unroll
    for (int off_ = 1; off_ <= 8; off_ <<= 1) {
        #pragma unroll
        for (int rt = 0; rt < 2; ++rt)
            #pragma unroll
            for (int j = 0; j < 4; ++j) {
                s[rt][j] += __shfl_xor(s[rt][j], off_);
                q2[rt][j] += __shfl_xor(q2[rt][j], off_);
            }
    }
    if (ll == 0) {
        #pragma unroll
        for (int rt = 0; rt < 2; ++rt)
            #pragma unroll
            for (int j = 0; j < 4; ++j) {
                red[w][rt*16 + lg*4 + j][0] = s[rt][j];
                red[w][rt*16 + lg*4 + j][1] = q2[rt][j];
            }
    }
    __syncthreads();

    #pragma unroll
    for (int rt = 0; rt < 2; ++rt) {
        #pragma unroll
        for (int j = 0; j < 4; ++j) {
            const int lr = rt*16 + lg*4 + j;
            const float S = red[2*wr][lr][0] + red[2*wr + 1][lr][0];
            const float Q = red[2*wr][lr][1] + red[2*wr + 1][lr][1];
            const float mu = S * (1.0f/DD);
            const float var = Q * (1.0f/DD) - mu*mu;
            const float inv = rsqrtf(var + 1e-5f);
            #pragma unroll
            for (int ct = 0; ct < 4; ++ct) {
                const float hn = (acc[rt][ct][j] - mu) * inv * g1v[ct] + be1v[ct];
                const float sv = hn / (1.0f + __expf(-hn));
                AnG[R0 + lr][C0 + ct*16 + ll] = f2bf(sv);
            }
        }
    }
    __syncthreads();

    f32x4 acc2[2][4] = {};
    #pragma unroll
    for (int kt = 0; kt < 4; ++kt) {
        const v8bf a0 = *(const v8bf*)&AnG[R0 + ll][kt*32 + lg*8];
        const v8bf a1 = *(const v8bf*)&AnG[R0 + 16 + ll][kt*32 + lg*8];
        #pragma unroll
        for (int ct = 0; ct < 4; ++ct) {
            const v8bf b = *(const v8bf*)&Wp2[((kt*8 + wc*4 + ct)*64 + lane)*8];
            acc2[0][ct] = __builtin_amdgcn_mfma_f32_16x16x32_bf16(a0, b, acc2[0][ct], 0, 0, 0);
            acc2[1][ct] = __builtin_amdgcn_mfma_f32_16x16x32_bf16(a1, b, acc2[1][ct], 0, 0, 0);
        }
    }

    #pragma unroll
    for (int rt = 0; rt < 2; ++rt)
        #pragma unroll
        for (int ct = 0; ct < 4; ++ct)
            #pragma unroll
            for (int j = 0; j < 4; ++j) {
                const long grow = base + R0 + rt*16 + lg*4 + j;
                if (grow < NODES) {
                    const int col = C0 + ct*16 + ll;
                    n_out[grow*DD + col] = n_in[grow*DD + col] + acc2[rt][ct][j] + b2v[ct];
                }
            }
}

extern "C" void kernel_launch(void* const* d_in, const int* in_sizes, int n_in,
                              void* d_out, int out_size, void* d_ws, size_t ws_size,
                              hipStream_t stream) {
    const float* node_feat = (const float*)d_in[0];
    const float* edge_attr = (const float*)d_in[1];
    const int*   edge_index= (const int*)d_in[2];
    const float* eW1 = (const float*)d_in[3];
    const float* eb1 = (const float*)d_in[4];
    const float* eg1 = (const float*)d_in[5];
    const float* ebe1= (const float*)d_in[6];
    const float* eW2 = (const float*)d_in[7];
    const float* eb2 = (const float*)d_in[8];
    const float* nW1 = (const float*)d_in[9];
    const float* nb1 = (const float*)d_in[10];
    const float* ng1 = (const float*)d_in[11];
    const float* nbe1= (const float*)d_in[12];
    const float* nW2 = (const float*)d_in[13];
    const float* nb2 = (const float*)d_in[14];

    const int N = NODES, E = EDGES;
    const int* src  = edge_index;
    const int* dstI = edge_index + E;

    float* out_n = (float*)d_out;
    float* out_e = (float*)d_out + (size_t)N * DD;

    // ws: [wp 458752 B]
    //     [ints @458752: deg 50000 | off 50001 | cursor 50000 | elist 256000 |
    //                    bsum 64 | bbase 64]
    //     [e1w 65.536 MB bf16 @ 2083840]
    //     [NG1 25.6  MB bf16 @ 67619840, if ws allows]
    unsigned short* wp = (unsigned short*)d_ws;
    int* ib     = (int*)((char*)d_ws + 458752);
    int* deg    = ib;
    int* off    = ib + 50000;
    int* cursor = ib + 100001;
    int* elist  = ib + 150001;
    int* bsum   = ib + 406001;
    int* bbase  = ib + 406065;
    unsigned short* e1w = (unsigned short*)((char*)d_ws + 2083840);
    unsigned short* NG1 = (unsigned short*)((char*)d_ws + 67619840);
    const bool big_ws = ws_size >= (67619840ull + (size_t)NODES*256*2 + 64);

    pack_weights<<<48, 512, 0, stream>>>(eW1, eW2, nW1, nW2, wp);

    hipMemsetAsync(deg, 0, (size_t)N * sizeof(int), stream);
    hist_kernel<<<(E + 255)/256, 256, 0, stream>>>(dstI, deg);
    scan_pass1<<<SCAN_BLOCKS, 256, 0, stream>>>(deg, bsum);
    scan_pass2<<<1, 64, 0, stream>>>(bsum, bbase);
    scan_pass3<<<SCAN_BLOCKS, 256, 0, stream>>>(deg, bbase, off, cursor);
    place_kernel<<<(E + 255)/256, 256, 0, stream>>>(dstI, cursor, elist);

    const int NB = (N + 63)/64;
    unsigned short* NG0 = (unsigned short*)out_e;   // dead space during layer 0

    // ---- layer 0 ----
    node_proj<<<NB, 256, 0, stream>>>(node_feat, wp + 32768, NG0);
    edge_mlp_ng<true><<<E/64, 256, 0, stream>>>(
        edge_attr, NG0, elist, src, dstI,
        wp, eb1, eg1, ebe1, wp + 98304, eb2, e1w, nullptr);
    node_mlp<true><<<NB, 256, 0, stream>>>(
        node_feat, e1w, off, elist,
        wp + 131072, nb1, ng1, nbe1, wp + 196608, nb2, out_n);

    // ---- layer 1 ----
    if (big_ws) {
        node_proj<<<NB, 256, 0, stream>>>(out_n, wp + 32768 + 32768, NG1);
        edge_mlp_ng<false><<<E/64, 256, 0, stream>>>(
            e1w, NG1, elist, src, dstI,
            wp + 16384, eb1 + DD, eg1 + DD, ebe1 + DD,
            wp + 98304 + 16384, eb2 + DD, e1w /*in-place e2w*/, out_e);
        node_mlp<true><<<NB, 256, 0, stream>>>(
            out_n, e1w, off, elist,
            wp + 131072 + 32768, nb1 + DD, ng1 + DD, nbe1 + DD,
            wp + 196608 + 16384, nb2 + DD, out_n);
    } else {
        edge_mlp_full<<<E/64, 256, 0, stream>>>(
            e1w, out_n, elist, src, dstI,
            wp + 16384, wp + 32768 + 32768,
            eb1 + DD, eg1 + DD, ebe1 + DD,
            wp + 98304 + 16384, eb2 + DD, out_e);
        node_mlp<false><<<NB, 256, 0, stream>>>(
            out_n, out_e, off, elist,
            wp + 131072 + 32768, nb1 + DD, ng1 + DD, nbe1 + DD,
            wp + 196608 + 16384, nb2 + DD, out_n);
    }
}

// Round 10
// 347.967 us; speedup vs baseline: 1.0672x; 1.0181x over previous
//
#include <hip/hip_runtime.h>
#include <hip/hip_bf16.h>

typedef float f32x4 __attribute__((ext_vector_type(4)));
typedef __bf16 v8bf __attribute__((ext_vector_type(8)));

#define DD 128
#define EDGES 256000
#define NODES 50000
#define SCAN_BLOCKS 49   // 49*1024 >= 50000

__device__ __forceinline__ unsigned short f2bf(float f) {
    union { float f; unsigned u; } v; v.f = f;
    unsigned r = v.u + 0x7fffu + ((v.u >> 16) & 1u);
    return (unsigned short)(r >> 16);
}
__device__ __forceinline__ float bf2f(unsigned short u) {
    union { unsigned u; float f; } v; v.u = ((unsigned)u) << 16; return v.f;
}

// ---------------------------------------------------------------------------
// Weight prep. Packed B-fragment layout for a [K x C] matrix:
//   dst[((kt*(C/16)+ct)*64+l)*8+j] = bf16(W[(kt*32+(l>>4)*8+j)*C + ct*16+(l&15)])
// wp layout (ushorts):
//   eW1a: layer*16384 | eWbc: 32768+layer*32768 | eW2: 98304+layer*16384
//   nW1: 131072+layer*32768 | nW2: 196608+layer*16384
// ---------------------------------------------------------------------------
__global__ __launch_bounds__(512)
void pack_weights(const float* __restrict__ eW1, const float* __restrict__ eW2,
                  const float* __restrict__ nW1, const float* __restrict__ nW2,
                  unsigned short* __restrict__ wp)
{
    const int b = blockIdx.x;            // 0..47
    const int layer = b / 24;
    const int u = b % 24;
    const int t = threadIdx.x;
    const int ct0 = t >> 6, l = t & 63;
    const int lg = l >> 4, ll = l & 15;

    if (u < 8 && u >= 4) {
        // eWbc: [128 x 256], Wbc[k][c] = eW1[128 + k + (c>=128?128:0)][c&127]
        const int kt = u - 4;
        const float* W = eW1 + layer*49152;
        unsigned short* dst = wp + 32768 + layer*32768;
        #pragma unroll
        for (int h = 0; h < 2; ++h) {
            const int ct = ct0 + h*8;
            #pragma unroll
            for (int j = 0; j < 8; ++j) {
                const int k = kt*32 + lg*8 + j;
                const int cout = ct*16 + ll;
                const int row = 128 + k + ((cout >= 128) ? 128 : 0);
                const int col = cout & 127;
                dst[((kt*16 + ct)*64 + l)*8 + j] = f2bf(W[row*128 + col]);
            }
        }
        return;
    }
    const float* W; int kt; unsigned short* dst;
    if (u < 4)       { W = eW1 + layer*49152; kt = u;      dst = wp + layer*16384; }
    else if (u < 12) { W = eW2 + layer*16384; kt = u - 8;  dst = wp + 98304 + layer*16384; }
    else if (u < 20) { W = nW1 + layer*32768; kt = u - 12; dst = wp + 131072 + layer*32768; }
    else             { W = nW2 + layer*16384; kt = u - 20; dst = wp + 196608 + layer*16384; }
    #pragma unroll
    for (int j = 0; j < 8; ++j) {
        const int k = kt*32 + lg*8 + j;
        const int c = ct0*16 + ll;
        dst[((kt*8 + ct0)*64 + l)*8 + j] = f2bf(W[k*128 + c]);
    }
}

// ---------------------------------------------------------------------------
// CSR build: histogram -> 3-pass multi-block scan -> placement
// ---------------------------------------------------------------------------
__global__ void hist_kernel(const int* __restrict__ dst, int* __restrict__ deg)
{
    const int i = blockIdx.x * blockDim.x + threadIdx.x;
    if (i < EDGES) atomicAdd(&deg[dst[i]], 1);
}

__global__ __launch_bounds__(256)
void scan_pass1(const int* __restrict__ deg, int* __restrict__ bsum)
{
    __shared__ int ws[256];
    const int b = blockIdx.x, t = threadIdx.x;
    const int base = b*1024 + t*4;
    int s = 0;
    #pragma unroll
    for (int k = 0; k < 4; ++k) {
        const int idx = base + k;
        if (idx < NODES) s += deg[idx];
    }
    ws[t] = s;
    __syncthreads();
    for (int d = 128; d >= 1; d >>= 1) {
        if (t < d) ws[t] += ws[t + d];
        __syncthreads();
    }
    if (t == 0) bsum[b] = ws[0];
}

__global__ __launch_bounds__(64)
void scan_pass2(const int* __restrict__ bsum, int* __restrict__ bbase)
{
    const int t = threadIdx.x;
    const int mine = (t < SCAN_BLOCKS) ? bsum[t] : 0;
    int v = mine;
    #pragma unroll
    for (int d = 1; d < 64; d <<= 1) {
        const int u = __shfl_up(v, d);
        if (t >= d) v += u;
    }
    if (t < SCAN_BLOCKS) bbase[t] = v - mine;   // exclusive
}

__global__ __launch_bounds__(256)
void scan_pass3(const int* __restrict__ deg, const int* __restrict__ bbase,
                int* __restrict__ off, int* __restrict__ cursor)
{
    __shared__ int ws[256];
    const int b = blockIdx.x, t = threadIdx.x;
    const int base = b*1024 + t*4;
    int d4[4]; int s = 0;
    #pragma unroll
    for (int k = 0; k < 4; ++k) {
        const int idx = base + k;
        d4[k] = (idx < NODES) ? deg[idx] : 0;
        s += d4[k];
    }
    ws[t] = s;
    __syncthreads();
    for (int d = 1; d < 256; d <<= 1) {
        const int u = (t >= d) ? ws[t - d] : 0;
        __syncthreads();
        ws[t] += u;
        __syncthreads();
    }
    int run = bbase[b] + ws[t] - s;   // exclusive prefix for this thread's chunk
    #pragma unroll
    for (int k = 0; k < 4; ++k) {
        const int idx = base + k;
        if (idx < NODES) { off[idx] = run; cursor[idx] = run; run += d4[k]; }
    }
    if (b == 0 && t == 0) off[NODES] = EDGES;
}

__global__ void place_kernel(const int* __restrict__ dst, int* __restrict__ cursor,
                             int* __restrict__ elist)
{
    const int i = blockIdx.x * blockDim.x + threadIdx.x;
    if (i < EDGES) {
        const int p = atomicAdd(&cursor[dst[i]], 1);
        elist[p] = i;
    }
}

// ---------------------------------------------------------------------------
// Node projection: NG[v] = bf16(n[v] @ Wbc) in wave-contiguous fragment order:
//   value (side, ct, ll) = col side*128 + ct*16 + ll  (ct in [0,8))
//   -> flat = side*128 + (ct>=4)*64 + ll*4 + (ct&3)
// ---------------------------------------------------------------------------
__global__ __launch_bounds__(256)
void node_proj(const float* __restrict__ n,
               const unsigned short* __restrict__ Wbc,
               unsigned short* __restrict__ NG)
{
    __shared__ __align__(16) unsigned short A[64][136];
    const int tid = threadIdx.x;
    const long base = (long)blockIdx.x * 64;

    #pragma unroll
    for (int it = 0; it < 8; ++it) {
        const int i = tid + it*256;
        const int row = i >> 5;
        const int c = (i & 31) * 4;
        float4 v = {0.f, 0.f, 0.f, 0.f};
        if (base + row < NODES) v = *(const float4*)&n[(base + row)*DD + c];
        ushort4 o; o.x = f2bf(v.x); o.y = f2bf(v.y); o.z = f2bf(v.z); o.w = f2bf(v.w);
        *(ushort4*)&A[row][c] = o;
    }
    __syncthreads();

    const int lane = tid & 63, w = tid >> 6;
    const int wr = w >> 1, wc = w & 1;   // wc = side
    const int R0 = wr*32;
    const int lg = lane >> 4, ll = lane & 15;

    f32x4 acc[2][8] = {};
    #pragma unroll
    for (int kt = 0; kt < 4; ++kt) {
        const v8bf a0 = *(const v8bf*)&A[R0 + ll][kt*32 + lg*8];
        const v8bf a1 = *(const v8bf*)&A[R0 + 16 + ll][kt*32 + lg*8];
        #pragma unroll
        for (int ct = 0; ct < 8; ++ct) {
            const v8bf b = *(const v8bf*)&Wbc[((kt*16 + wc*8 + ct)*64 + lane)*8];
            acc[0][ct] = __builtin_amdgcn_mfma_f32_16x16x32_bf16(a0, b, acc[0][ct], 0, 0, 0);
            acc[1][ct] = __builtin_amdgcn_mfma_f32_16x16x32_bf16(a1, b, acc[1][ct], 0, 0, 0);
        }
    }

    #pragma unroll
    for (int rt = 0; rt < 2; ++rt)
        #pragma unroll
        for (int j = 0; j < 4; ++j) {
            const long grow = base + R0 + rt*16 + lg*4 + j;
            if (grow < NODES) {
                ushort4 o0, o1;
                o0.x = f2bf(acc[rt][0][j]); o0.y = f2bf(acc[rt][1][j]);
                o0.z = f2bf(acc[rt][2][j]); o0.w = f2bf(acc[rt][3][j]);
                o1.x = f2bf(acc[rt][4][j]); o1.y = f2bf(acc[rt][5][j]);
                o1.z = f2bf(acc[rt][6][j]); o1.w = f2bf(acc[rt][7][j]);
                *(ushort4*)&NG[grow*256 + wc*128 + ll*4]      = o0;
                *(ushort4*)&NG[grow*256 + wc*128 + 64 + ll*4] = o1;
            }
        }
}

// ---------------------------------------------------------------------------
// Edge MLP (dst-sorted order), 128 threads / 2 waves / 32 rows per block.
// Per-wave redundant index copies remove the idx barrier; 3 light barriers
// sync only 2 waves. LDS ~18.7KB -> 8 blocks/CU.
// ---------------------------------------------------------------------------
template <bool L0>
__global__ __launch_bounds__(128, 4)
void edge_mlp_ng(const void* __restrict__ e_in_v,
                 const unsigned short* __restrict__ NG,
                 const int* __restrict__ elist,
                 const int* __restrict__ srcA, const int* __restrict__ dstA,
                 const unsigned short* __restrict__ Wa,
                 const float* __restrict__ b1, const float* __restrict__ g1,
                 const float* __restrict__ be1,
                 const unsigned short* __restrict__ Wp2,
                 const float* __restrict__ b2,
                 unsigned short* __restrict__ ePw,
                 float* __restrict__ e_out)
{
    __shared__ __align__(16) unsigned short AeE[32][136];
    __shared__ __align__(16) unsigned short Sl[32][136];
    __shared__ float red[2][32][2];
    __shared__ int gidx[2][96];   // per-wave copy: [e 0-31 | src 32-63 | dst 64-95]

    const int tid = threadIdx.x;
    const long base = (long)blockIdx.x * 32;
    const int lane = tid & 63, wc = tid >> 6;
    const int C0 = wc*64;
    const int lg = lane >> 4, ll = lane & 15;

    // per-wave index load (no block barrier needed: same-wave LDS)
    int* g = gidx[wc];
    if (lane < 32) {
        const int e = elist[base + lane];
        g[lane] = e;
        g[32 + lane] = srcA[e];
        g[64 + lane] = dstA[e];
    }

    // stage e tile (issued first: GEMM1a depends on it)
    if constexpr (L0) {
        const float* e_in = (const float*)e_in_v;
        #pragma unroll
        for (int it = 0; it < 8; ++it) {
            const int i = tid + it*128;
            const int row = i >> 5;
            const int c = (i & 31) * 4;
            const float4 v = *(const float4*)&e_in[(long)g[row]*DD + c];
            ushort4 o; o.x = f2bf(v.x); o.y = f2bf(v.y); o.z = f2bf(v.z); o.w = f2bf(v.w);
            *(ushort4*)&AeE[row][c] = o;
        }
    } else {
        const unsigned short* e_in = (const unsigned short*)e_in_v;
        #pragma unroll
        for (int it = 0; it < 4; ++it) {
            const int i = tid + it*128;
            const int row = i >> 4;
            const int c = (i & 15) * 8;
            *(uint4*)&AeE[row][c] = *(const uint4*)&e_in[(base + row)*DD + c];
        }
    }

    // NG prefetch (latency hides under staging + GEMM1a)
    ushort4 ngs[2][4], ngd[2][4];
    #pragma unroll
    for (int rt = 0; rt < 2; ++rt)
        #pragma unroll
        for (int j = 0; j < 4; ++j) {
            const int lr = rt*16 + lg*4 + j;
            const long sid = g[32 + lr];
            const long did = g[64 + lr];
            ngs[rt][j] = *(const ushort4*)&NG[sid*256 + wc*64 + ll*4];
            ngd[rt][j] = *(const ushort4*)&NG[did*256 + 128 + wc*64 + ll*4];
        }
    __syncthreads();   // stage complete (2 waves)

    float b1v[4], g1v[4], be1v[4], b2v[4];
    #pragma unroll
    for (int ct = 0; ct < 4; ++ct) {
        const int c = C0 + ct*16 + ll;
        b1v[ct] = b1[c]; g1v[ct] = g1[c]; be1v[ct] = be1[c]; b2v[ct] = b2[c];
    }

    // GEMM1a: eP @ W1a (K=128)
    f32x4 acc[2][4] = {};
    #pragma unroll
    for (int kt = 0; kt < 4; ++kt) {
        const v8bf a0 = *(const v8bf*)&AeE[ll][kt*32 + lg*8];
        const v8bf a1 = *(const v8bf*)&AeE[16 + ll][kt*32 + lg*8];
        #pragma unroll
        for (int ct = 0; ct < 4; ++ct) {
            const v8bf b = *(const v8bf*)&Wa[((kt*8 + wc*4 + ct)*64 + lane)*8];
            acc[0][ct] = __builtin_amdgcn_mfma_f32_16x16x32_bf16(a0, b, acc[0][ct], 0, 0, 0);
            acc[1][ct] = __builtin_amdgcn_mfma_f32_16x16x32_bf16(a1, b, acc[1][ct], 0, 0, 0);
        }
    }

    // + NG[src] + NG[dst] from prefetched registers
    #pragma unroll
    for (int rt = 0; rt < 2; ++rt)
        #pragma unroll
        for (int j = 0; j < 4; ++j) {
            const unsigned short* ps = (const unsigned short*)&ngs[rt][j];
            const unsigned short* pd = (const unsigned short*)&ngd[rt][j];
            #pragma unroll
            for (int ct = 0; ct < 4; ++ct)
                acc[rt][ct][j] += bf2f(ps[ct]) + bf2f(pd[ct]);
        }

    // bias + LN stats
    f32x4 s[2], q[2];
    #pragma unroll
    for (int rt = 0; rt < 2; ++rt) {
        #pragma unroll
        for (int ct = 0; ct < 4; ++ct) acc[rt][ct] += b1v[ct];
        s[rt] = acc[rt][0] + acc[rt][1] + acc[rt][2] + acc[rt][3];
        q[rt] = acc[rt][0]*acc[rt][0] + acc[rt][1]*acc[rt][1]
              + acc[rt][2]*acc[rt][2] + acc[rt][3]*acc[rt][3];
    }
    #pragma unroll
    for (int off = 1; off <= 8; off <<= 1) {
        #pragma unroll
        for (int rt = 0; rt < 2; ++rt)
            #pragma unroll
            for (int j = 0; j < 4; ++j) {
                s[rt][j] += __shfl_xor(s[rt][j], off);
                q[rt][j] += __shfl_xor(q[rt][j], off);
            }
    }
    if (ll == 0) {
        #pragma unroll
        for (int rt = 0; rt < 2; ++rt)
            #pragma unroll
            for (int j = 0; j < 4; ++j) {
                red[wc][rt*16 + lg*4 + j][0] = s[rt][j];
                red[wc][rt*16 + lg*4 + j][1] = q[rt][j];
            }
    }
    __syncthreads();

    // LN + SiLU -> Sl
    #pragma unroll
    for (int rt = 0; rt < 2; ++rt) {
        #pragma unroll
        for (int j = 0; j < 4; ++j) {
            const int lr = rt*16 + lg*4 + j;
            const float S = red[0][lr][0] + red[1][lr][0];
            const float Q = red[0][lr][1] + red[1][lr][1];
            const float mu = S * (1.0f/DD);
            const float var = Q * (1.0f/DD) - mu*mu;
            const float inv = rsqrtf(var + 1e-5f);
            #pragma unroll
            for (int ct = 0; ct < 4; ++ct) {
                const float hn = (acc[rt][ct][j] - mu) * inv * g1v[ct] + be1v[ct];
                const float sv = hn / (1.0f + __expf(-hn));
                Sl[lr][C0 + ct*16 + ll] = f2bf(sv);
            }
        }
    }
    __syncthreads();

    // GEMM2
    f32x4 acc2[2][4] = {};
    #pragma unroll
    for (int kt = 0; kt < 4; ++kt) {
        const v8bf a0 = *(const v8bf*)&Sl[ll][kt*32 + lg*8];
        const v8bf a1 = *(const v8bf*)&Sl[16 + ll][kt*32 + lg*8];
        #pragma unroll
        for (int ct = 0; ct < 4; ++ct) {
            const v8bf b = *(const v8bf*)&Wp2[((kt*8 + wc*4 + ct)*64 + lane)*8];
            acc2[0][ct] = __builtin_amdgcn_mfma_f32_16x16x32_bf16(a0, b, acc2[0][ct], 0, 0, 0);
            acc2[1][ct] = __builtin_amdgcn_mfma_f32_16x16x32_bf16(a1, b, acc2[1][ct], 0, 0, 0);
        }
    }

    // residual + store
    #pragma unroll
    for (int rt = 0; rt < 2; ++rt)
        #pragma unroll
        for (int ct = 0; ct < 4; ++ct)
            #pragma unroll
            for (int j = 0; j < 4; ++j) {
                const int lr = rt*16 + lg*4 + j;
                const int col = C0 + ct*16 + ll;
                const float v = bf2f(AeE[lr][col]) + acc2[rt][ct][j] + b2v[ct];
                ePw[(base + lr)*DD + col] = f2bf(v);
                if constexpr (!L0)
                    e_out[(long)g[lr]*DD + col] = v;
            }
}

// ---------------------------------------------------------------------------
// Full-K edge MLP fallback (layer 1 without NG1 space)
// ---------------------------------------------------------------------------
__global__ __launch_bounds__(256, 4)
void edge_mlp_full(const unsigned short* __restrict__ e_in,
                   const float* __restrict__ nf,
                   const int* __restrict__ elist,
                   const int* __restrict__ srcA, const int* __restrict__ dstA,
                   const unsigned short* __restrict__ Wa,
                   const unsigned short* __restrict__ Wbc,
                   const float* __restrict__ b1, const float* __restrict__ g1,
                   const float* __restrict__ be1,
                   const unsigned short* __restrict__ Wp2,
                   const float* __restrict__ b2, float* __restrict__ e_out)
{
    __shared__ __align__(16) unsigned short AeE[64][136];
    __shared__ __align__(16) unsigned short AeG[64][132];
    __shared__ float red[4][32][2];
    __shared__ int eidx[64], sidx[64], didx[64];

    const int tid = threadIdx.x;
    const long base = (long)blockIdx.x * 64;

    if (tid < 64) {
        const int i = elist[base + tid];
        eidx[tid] = i; sidx[tid] = srcA[i]; didx[tid] = dstA[i];
    }

    const int lane = tid & 63, w = tid >> 6;
    const int wr = w >> 1, wc = w & 1;
    const int R0 = wr*32, C0 = wc*64;
    const int lg = lane >> 4, ll = lane & 15;

    #pragma unroll
    for (int it = 0; it < 4; ++it) {
        const int i = tid + it*256;
        const int row = i >> 4;
        const int c = (i & 15) * 8;
        *(uint4*)&AeE[row][c] = *(const uint4*)&e_in[(base + row)*DD + c];
    }
    __syncthreads();

    #pragma unroll
    for (int it = 0; it < 8; ++it) {
        const int i = tid + it*256;
        const int row = i >> 5;
        const int c = (i & 31) * 4;
        const float4 v = *(const float4*)&nf[(long)sidx[row]*DD + c];
        ushort4 o; o.x = f2bf(v.x); o.y = f2bf(v.y); o.z = f2bf(v.z); o.w = f2bf(v.w);
        *(ushort4*)&AeG[row][c] = o;
    }
    float4 dreg[8];
    #pragma unroll
    for (int it = 0; it < 8; ++it) {
        const int i = tid + it*256;
        const int row = i >> 5;
        const int c = (i & 31) * 4;
        dreg[it] = *(const float4*)&nf[(long)didx[row]*DD + c];
    }
    __syncthreads();

    float b1v[4], g1v[4], be1v[4], b2v[4];
    #pragma unroll
    for (int ct = 0; ct < 4; ++ct) {
        const int c = C0 + ct*16 + ll;
        b1v[ct] = b1[c]; g1v[ct] = g1[c]; be1v[ct] = be1[c]; b2v[ct] = b2[c];
    }

    f32x4 acc[2][4] = {};
    #pragma unroll
    for (int kt = 0; kt < 8; ++kt) {
        const unsigned short* a0p = (kt < 4) ? &AeE[R0 + ll][kt*32 + lg*8]
                                             : &AeG[R0 + ll][(kt-4)*32 + lg*8];
        const unsigned short* a1p = (kt < 4) ? &AeE[R0 + 16 + ll][kt*32 + lg*8]
                                             : &AeG[R0 + 16 + ll][(kt-4)*32 + lg*8];
        const v8bf a0 = *(const v8bf*)a0p;
        const v8bf a1 = *(const v8bf*)a1p;
        #pragma unroll
        for (int ct = 0; ct < 4; ++ct) {
            const v8bf b = (kt < 4)
                ? *(const v8bf*)&Wa[((kt*8 + wc*4 + ct)*64 + lane)*8]
                : *(const v8bf*)&Wbc[(((kt-4)*16 + wc*4 + ct)*64 + lane)*8];
            acc[0][ct] = __builtin_amdgcn_mfma_f32_16x16x32_bf16(a0, b, acc[0][ct], 0, 0, 0);
            acc[1][ct] = __builtin_amdgcn_mfma_f32_16x16x32_bf16(a1, b, acc[1][ct], 0, 0, 0);
        }
    }
    __syncthreads();

    #pragma unroll
    for (int it = 0; it < 8; ++it) {
        const int i = tid + it*256;
        const int row = i >> 5;
        const int c = (i & 31) * 4;
        ushort4 o; o.x = f2bf(dreg[it].x); o.y = f2bf(dreg[it].y);
        o.z = f2bf(dreg[it].z); o.w = f2bf(dreg[it].w);
        *(ushort4*)&AeG[row][c] = o;
    }
    __syncthreads();

    #pragma unroll
    for (int kt = 0; kt < 4; ++kt) {
        const v8bf a0 = *(const v8bf*)&AeG[R0 + ll][kt*32 + lg*8];
        const v8bf a1 = *(const v8bf*)&AeG[R0 + 16 + ll][kt*32 + lg*8];
        #pragma unroll
        for (int ct = 0; ct < 4; ++ct) {
            const v8bf b = *(const v8bf*)&Wbc[((kt*16 + 8 + wc*4 + ct)*64 + lane)*8];
            acc[0][ct] = __builtin_amdgcn_mfma_f32_16x16x32_bf16(a0, b, acc[0][ct], 0, 0, 0);
            acc[1][ct] = __builtin_amdgcn_mfma_f32_16x16x32_bf16(a1, b, acc[1][ct], 0, 0, 0);
        }
    }

    f32x4 s[2], q[2];
    #pragma unroll
    for (int rt = 0; rt < 2; ++rt) {
        #pragma unroll
        for (int ct = 0; ct < 4; ++ct) acc[rt][ct] += b1v[ct];
        s[rt] = acc[rt][0] + acc[rt][1] + acc[rt][2] + acc[rt][3];
        q[rt] = acc[rt][0]*acc[rt][0] + acc[rt][1]*acc[rt][1]
              + acc[rt][2]*acc[rt][2] + acc[rt][3]*acc[rt][3];
    }
    #pragma unroll
    for (int off = 1; off <= 8; off <<= 1) {
        #pragma unroll
        for (int rt = 0; rt < 2; ++rt)
            #pragma unroll
            for (int j = 0; j < 4; ++j) {
                s[rt][j] += __shfl_xor(s[rt][j], off);
                q[rt][j] += __shfl_xor(q[rt][j], off);
            }
    }
    if (ll == 0) {
        #pragma unroll
        for (int rt = 0; rt < 2; ++rt)
            #pragma unroll
            for (int j = 0; j < 4; ++j) {
                red[w][rt*16 + lg*4 + j][0] = s[rt][j];
                red[w][rt*16 + lg*4 + j][1] = q[rt][j];
            }
    }
    __syncthreads();

    #pragma unroll
    for (int rt = 0; rt < 2; ++rt) {
        #pragma unroll
        for (int j = 0; j < 4; ++j) {
            const int lr = rt*16 + lg*4 + j;
            const float S = red[2*wr][lr][0] + red[2*wr + 1][lr][0];
            const float Q = red[2*wr][lr][1] + red[2*wr + 1][lr][1];
            const float mu = S * (1.0f/DD);
            const float var = Q * (1.0f/DD) - mu*mu;
            const float inv = rsqrtf(var + 1e-5f);
            #pragma unroll
            for (int ct = 0; ct < 4; ++ct) {
                const float hn = (acc[rt][ct][j] - mu) * inv * g1v[ct] + be1v[ct];
                const float sv = hn / (1.0f + __expf(-hn));
                AeG[R0 + lr][C0 + ct*16 + ll] = f2bf(sv);
            }
        }
    }
    __syncthreads();

    f32x4 acc2[2][4] = {};
    #pragma unroll
    for (int kt = 0; kt < 4; ++kt) {
        const v8bf a0 = *(const v8bf*)&AeG[R0 + ll][kt*32 + lg*8];
        const v8bf a1 = *(const v8bf*)&AeG[R0 + 16 + ll][kt*32 + lg*8];
        #pragma unroll
        for (int ct = 0; ct < 4; ++ct) {
            const v8bf b = *(const v8bf*)&Wp2[((kt*8 + wc*4 + ct)*64 + lane)*8];
            acc2[0][ct] = __builtin_amdgcn_mfma_f32_16x16x32_bf16(a0, b, acc2[0][ct], 0, 0, 0);
            acc2[1][ct] = __builtin_amdgcn_mfma_f32_16x16x32_bf16(a1, b, acc2[1][ct], 0, 0, 0);
        }
    }

    #pragma unroll
    for (int rt = 0; rt < 2; ++rt)
        #pragma unroll
        for (int ct = 0; ct < 4; ++ct)
            #pragma unroll
            for (int j = 0; j < 4; ++j) {
                const int lr = rt*16 + lg*4 + j;
                const int col = C0 + ct*16 + ll;
                const float v = bf2f(AeE[R0 + lr][col]) + acc2[rt][ct][j] + b2v[ct];
                e_out[(long)eidx[R0 + lr]*DD + col] = v;
            }
}

// ---------------------------------------------------------------------------
// Node MLP with CSR gather-aggregate.
// ---------------------------------------------------------------------------
template <bool SEQ>
__global__ __launch_bounds__(256)
void node_mlp(const float* n_in, const void* __restrict__ e_buf_v,
              const int* __restrict__ off, const int* __restrict__ elist,
              const unsigned short* __restrict__ Wp1,
              const float* __restrict__ b1, const float* __restrict__ g1,
              const float* __restrict__ be1,
              const unsigned short* __restrict__ Wp2,
              const float* __restrict__ b2, float* n_out)
{
    __shared__ __align__(16) unsigned short AnN[64][136];
    __shared__ __align__(16) unsigned short AnG[64][136];
    __shared__ float red[4][32][2];

    const int tid = threadIdx.x;
    const long base = (long)blockIdx.x * 64;

    const int lane = tid & 63, w = tid >> 6;
    const int wr = w >> 1, wc = w & 1;
    const int R0 = wr*32, C0 = wc*64;
    const int lg = lane >> 4, ll = lane & 15;

    float b1v[4], g1v[4], be1v[4], b2v[4];
    #pragma unroll
    for (int ct = 0; ct < 4; ++ct) {
        const int c = C0 + ct*16 + ll;
        b1v[ct] = b1[c]; g1v[ct] = g1[c]; be1v[ct] = be1[c]; b2v[ct] = b2[c];
    }

    // gather-aggregate: 4 threads/row x 32 cols
    {
        const int r  = tid >> 2;
        const int cq = (tid & 3) * 32;
        const long row = base + r;
        float a[32];
        #pragma unroll
        for (int q = 0; q < 32; ++q) a[q] = 0.f;
        if (row < NODES) {
            const int jb = off[row], je = off[row + 1];
            for (int j = jb; j < je; ++j) {
                if constexpr (SEQ) {
                    const unsigned short* p = (const unsigned short*)e_buf_v + (long)j*DD + cq;
                    #pragma unroll
                    for (int u = 0; u < 4; ++u) {
                        const uint4 v = *(const uint4*)(p + u*8);
                        a[u*8+0] += bf2f((unsigned short)(v.x & 0xffff));
                        a[u*8+1] += bf2f((unsigned short)(v.x >> 16));
                        a[u*8+2] += bf2f((unsigned short)(v.y & 0xffff));
                        a[u*8+3] += bf2f((unsigned short)(v.y >> 16));
                        a[u*8+4] += bf2f((unsigned short)(v.z & 0xffff));
                        a[u*8+5] += bf2f((unsigned short)(v.z >> 16));
                        a[u*8+6] += bf2f((unsigned short)(v.w & 0xffff));
                        a[u*8+7] += bf2f((unsigned short)(v.w >> 16));
                    }
                } else {
                    const float* p = (const float*)e_buf_v + (long)elist[j]*DD + cq;
                    #pragma unroll
                    for (int q = 0; q < 8; ++q) {
                        const float4 v = *(const float4*)(p + q*4);
                        a[q*4+0] += v.x; a[q*4+1] += v.y;
                        a[q*4+2] += v.z; a[q*4+3] += v.w;
                    }
                }
            }
        }
        #pragma unroll
        for (int q = 0; q < 8; ++q) {
            ushort4 o;
            o.x = f2bf(a[q*4+0]); o.y = f2bf(a[q*4+1]);
            o.z = f2bf(a[q*4+2]); o.w = f2bf(a[q*4+3]);
            *(ushort4*)&AnG[r][cq + q*4] = o;
        }
    }

    #pragma unroll
    for (int it = 0; it < 8; ++it) {
        const int i = tid + it*256;
        const int row = i >> 5;
        const int c = (i & 31) * 4;
        float4 v = {0.f, 0.f, 0.f, 0.f};
        if (base + row < NODES) v = *(const float4*)&n_in[(base + row)*DD + c];
        ushort4 o; o.x = f2bf(v.x); o.y = f2bf(v.y); o.z = f2bf(v.z); o.w = f2bf(v.w);
        *(ushort4*)&AnN[row][c] = o;
    }
    __syncthreads();

    f32x4 acc[2][4] = {};
    #pragma unroll
    for (int kt = 0; kt < 8; ++kt) {
        const unsigned short* a0p = (kt < 4) ? &AnN[R0 + ll][kt*32 + lg*8]
                                             : &AnG[R0 + ll][(kt-4)*32 + lg*8];
        const unsigned short* a1p = (kt < 4) ? &AnN[R0 + 16 + ll][kt*32 + lg*8]
                                             : &AnG[R0 + 16 + ll][(kt-4)*32 + lg*8];
        const v8bf a0 = *(const v8bf*)a0p;
        const v8bf a1 = *(const v8bf*)a1p;
        #pragma unroll
        for (int ct = 0; ct < 4; ++ct) {
            const v8bf b = *(const v8bf*)&Wp1[((kt*8 + wc*4 + ct)*64 + lane)*8];
            acc[0][ct] = __builtin_amdgcn_mfma_f32_16x16x32_bf16(a0, b, acc[0][ct], 0, 0, 0);
            acc[1][ct] = __builtin_amdgcn_mfma_f32_16x16x32_bf16(a1, b, acc[1][ct], 0, 0, 0);
        }
    }

    f32x4 s[2], q2[2];
    #pragma unroll
    for (int rt = 0; rt < 2; ++rt) {
        #pragma unroll
        for (int ct = 0; ct < 4; ++ct) acc[rt][ct] += b1v[ct];
        s[rt] = acc[rt][0] + acc[rt][1] + acc[rt][2] + acc[rt][3];
        q2[rt] = acc[rt][0]*acc[rt][0] + acc[rt][1]*acc[rt][1]
               + acc[rt][2]*acc[rt][2] + acc[rt][3]*acc[rt][3];
    }
    #pragma unroll
    for (int off_ = 1; off_ <= 8; off_ <<= 1) {
        #pragma unroll
        for (int rt = 0; rt < 2; ++rt)
            #pragma unroll
            for (int j = 0; j < 4; ++j) {
                s[rt][j] += __shfl_xor(s[rt][j], off_);
                q2[rt][j] += __shfl_xor(q2[rt][j], off_);
            }
    }
    if (ll == 0) {
        #pragma unroll
        for (int rt = 0; rt < 2; ++rt)
            #pragma unroll
            for (int j = 0; j < 4; ++j) {
                red[w][rt*16 + lg*4 + j][0] = s[rt][j];
                red[w][rt*16 + lg*4 + j][1] = q2[rt][j];
            }
    }
    __syncthreads();

    #pragma unroll
    for (int rt = 0; rt < 2; ++rt) {
        #pragma unroll
        for (int j = 0; j < 4; ++j) {
            const int lr = rt*16 + lg*4 + j;
            const float S = red[2*wr][lr][0] + red[2*wr + 1][lr][0];
            const float Q = red[2*wr][lr][1] + red[2*wr + 1][lr][1];
            const float mu = S * (1.0f/DD);
            const float var = Q * (1.0f/DD) - mu*mu;
            const float inv = rsqrtf(var + 1e-5f);
            #pragma unroll
            for (int ct = 0; ct < 4; ++ct) {
                const float hn = (acc[rt][ct][j] - mu) * inv * g1v[ct] + be1v[ct];
                const float sv = hn / (1.0f + __expf(-hn));
                AnG[R0 + lr][C0 + ct*16 + ll] = f2bf(sv);
            }
        }
    }
    __syncthreads();

    f32x4 acc2[2][4] = {};
    #pragma unroll
    for (int kt = 0; kt < 4; ++kt) {
        const v8bf a0 = *(const v8bf*)&AnG[R0 + ll][kt*32 + lg*8];
        const v8bf a1 = *(const v8bf*)&AnG[R0 + 16 + ll][kt*32 + lg*8];
        #pragma unroll
        for (int ct = 0; ct < 4; ++ct) {
            const v8bf b = *(const v8bf*)&Wp2[((kt*8 + wc*4 + ct)*64 + lane)*8];
            acc2[0][ct] = __builtin_amdgcn_mfma_f32_16x16x32_bf16(a0, b, acc2[0][ct], 0, 0, 0);
            acc2[1][ct] = __builtin_amdgcn_mfma_f32_16x16x32_bf16(a1, b, acc2[1][ct], 0, 0, 0);
        }
    }

    #pragma unroll
    for (int rt = 0; rt < 2; ++rt)
        #pragma unroll
        for (int ct = 0; ct < 4; ++ct)
            #pragma unroll
            for (int j = 0; j < 4; ++j) {
                const long grow = base + R0 + rt*16 + lg*4 + j;
                if (grow < NODES) {
                    const int col = C0 + ct*16 + ll;
                    n_out[grow*DD + col] = n_in[grow*DD + col] + acc2[rt][ct][j] + b2v[ct];
                }
            }
}

extern "C" void kernel_launch(void* const* d_in, const int* in_sizes, int n_in,
                              void* d_out, int out_size, void* d_ws, size_t ws_size,
                              hipStream_t stream) {
    const float* node_feat = (const float*)d_in[0];
    const float* edge_attr = (const float*)d_in[1];
    const int*   edge_index= (const int*)d_in[2];
    const float* eW1 = (const float*)d_in[3];
    const float* eb1 = (const float*)d_in[4];
    const float* eg1 = (const float*)d_in[5];
    const float* ebe1= (const float*)d_in[6];
    const float* eW2 = (const float*)d_in[7];
    const float* eb2 = (const float*)d_in[8];
    const float* nW1 = (const float*)d_in[9];
    const float* nb1 = (const float*)d_in[10];
    const float* ng1 = (const float*)d_in[11];
    const float* nbe1= (const float*)d_in[12];
    const float* nW2 = (const float*)d_in[13];
    const float* nb2 = (const float*)d_in[14];

    const int N = NODES, E = EDGES;
    const int* src  = edge_index;
    const int* dstI = edge_index + E;

    float* out_n = (float*)d_out;
    float* out_e = (float*)d_out + (size_t)N * DD;

    // ws: [wp 458752 B]
    //     [ints @458752: deg 50000 | off 50001 | cursor 50000 | elist 256000 |
    //                    bsum 64 | bbase 64]
    //     [e1w 65.536 MB bf16 @ 2083840]
    //     [NG1 25.6  MB bf16 @ 67619840, if ws allows]
    unsigned short* wp = (unsigned short*)d_ws;
    int* ib     = (int*)((char*)d_ws + 458752);
    int* deg    = ib;
    int* off    = ib + 50000;
    int* cursor = ib + 100001;
    int* elist  = ib + 150001;
    int* bsum   = ib + 406001;
    int* bbase  = ib + 406065;
    unsigned short* e1w = (unsigned short*)((char*)d_ws + 2083840);
    unsigned short* NG1 = (unsigned short*)((char*)d_ws + 67619840);
    const bool big_ws = ws_size >= (67619840ull + (size_t)NODES*256*2 + 64);

    pack_weights<<<48, 512, 0, stream>>>(eW1, eW2, nW1, nW2, wp);

    hipMemsetAsync(deg, 0, (size_t)N * sizeof(int), stream);
    hist_kernel<<<(E + 255)/256, 256, 0, stream>>>(dstI, deg);
    scan_pass1<<<SCAN_BLOCKS, 256, 0, stream>>>(deg, bsum);
    scan_pass2<<<1, 64, 0, stream>>>(bsum, bbase);
    scan_pass3<<<SCAN_BLOCKS, 256, 0, stream>>>(deg, bbase, off, cursor);
    place_kernel<<<(E + 255)/256, 256, 0, stream>>>(dstI, cursor, elist);

    const int NB = (N + 63)/64;
    unsigned short* NG0 = (unsigned short*)out_e;   // dead space during layer 0

    // ---- layer 0 ----
    node_proj<<<NB, 256, 0, stream>>>(node_feat, wp + 32768, NG0);
    edge_mlp_ng<true><<<E/32, 128, 0, stream>>>(
        edge_attr, NG0, elist, src, dstI,
        wp, eb1, eg1, ebe1, wp + 98304, eb2, e1w, nullptr);
    node_mlp<true><<<NB, 256, 0, stream>>>(
        node_feat, e1w, off, elist,
        wp + 131072, nb1, ng1, nbe1, wp + 196608, nb2, out_n);

    // ---- layer 1 ----
    if (big_ws) {
        node_proj<<<NB, 256, 0, stream>>>(out_n, wp + 32768 + 32768, NG1);
        edge_mlp_ng<false><<<E/32, 128, 0, stream>>>(
            e1w, NG1, elist, src, dstI,
            wp + 16384, eb1 + DD, eg1 + DD, ebe1 + DD,
            wp + 98304 + 16384, eb2 + DD, e1w /*in-place e2w*/, out_e);
        node_mlp<true><<<NB, 256, 0, stream>>>(
            out_n, e1w, off, elist,
            wp + 131072 + 32768, nb1 + DD, ng1 + DD, nbe1 + DD,
            wp + 196608 + 16384, nb2 + DD, out_n);
    } else {
        edge_mlp_full<<<E/64, 256, 0, stream>>>(
            e1w, out_n, elist, src, dstI,
            wp + 16384, wp + 32768 + 32768,
            eb1 + DD, eg1 + DD, ebe1 + DD,
            wp + 98304 + 16384, eb2 + DD, out_e);
        node_mlp<false><<<NB, 256, 0, stream>>>(
            out_n, out_e, off, elist,
            wp + 131072 + 32768, nb1 + DD, ng1 + DD, nbe1 + DD,
            wp + 196608 + 16384, nb2 + DD, out_n);
    }
}